// Round 7
// baseline (381.279 us; speedup 1.0000x reference)
//
#include <hip/hip_runtime.h>
#include <math.h>
#include <stdint.h>

#define T_TOK 8192
#define HDIM 1024
#define IDIM 512
#define NEXP 8
#define NGRP 2
#define EPG 4

typedef unsigned short u16;
typedef __attribute__((ext_vector_type(8))) short short8;   // 8 bf16 in 4 VGPRs
typedef __attribute__((ext_vector_type(4))) float f32x4;

// async global->LDS, 16B per lane; LDS dest is wave-uniform base (HW adds lane*16)
#define GLD16(gp, lp) __builtin_amdgcn_global_load_lds(                        \
    (const __attribute__((address_space(1))) unsigned int*)(gp),               \
    (__attribute__((address_space(3))) unsigned int*)(lp), 16, 0, 0)

__device__ __forceinline__ u16 f2bf(float f) {  // RNE float->bf16
    unsigned int u = __float_as_uint(f);
    u += 0x7fffu + ((u >> 16) & 1u);
    return (u16)(u >> 16);
}
__device__ __forceinline__ float bf2f(u16 v) {
    return __uint_as_float(((unsigned int)v) << 16);
}

// ---------------- router: one wave per token; no atomics ----------------
__global__ __launch_bounds__(256)
void router_kernel(const float* __restrict__ X,
                   const float* __restrict__ Wr,    // [E,H]
                   const float* __restrict__ bias,  // [E]
                   u16* __restrict__ Xb,            // [T,H] bf16 out
                   float* __restrict__ wpair,       // [2T]
                   int* __restrict__ topk_ids)      // [T] packed i0 | i1<<8
{
    int wave = threadIdx.x >> 6;
    int lane = threadIdx.x & 63;
    int t = blockIdx.x * 4 + wave;
    if (t >= T_TOK) return;

    float acc[NEXP];
#pragma unroll
    for (int e = 0; e < NEXP; ++e) acc[e] = 0.f;

    const float4* X4 = (const float4*)(X + (size_t)t * HDIM);
#pragma unroll
    for (int jj = 0; jj < 4; ++jj) {
        float4 xv = X4[lane + jj * 64];
        ushort4 bv;
        bv.x = f2bf(xv.x); bv.y = f2bf(xv.y); bv.z = f2bf(xv.z); bv.w = f2bf(xv.w);
        *(ushort4*)(Xb + (size_t)t * HDIM + (size_t)(lane + jj * 64) * 4) = bv;
#pragma unroll
        for (int e = 0; e < NEXP; ++e) {
            const float4* W4 = (const float4*)(Wr + (size_t)e * HDIM);
            float4 wv = W4[lane + jj * 64];
            acc[e] += xv.x * wv.x + xv.y * wv.y + xv.z * wv.z + xv.w * wv.w;
        }
    }
#pragma unroll
    for (int e = 0; e < NEXP; ++e) {
#pragma unroll
        for (int off = 32; off >= 1; off >>= 1)
            acc[e] += __shfl_xor(acc[e], off, 64);
    }

    if (lane == 0) {
        float s[NEXP], b[NEXP];
#pragma unroll
        for (int e = 0; e < NEXP; ++e) {
            s[e] = 1.f / (1.f + expf(-acc[e]));
            b[e] = s[e] + bias[e];
        }
        float gs[NGRP];
#pragma unroll
        for (int g = 0; g < NGRP; ++g) {
            float m1 = -1e30f, m2 = -1e30f;
#pragma unroll
            for (int j = 0; j < EPG; ++j) {
                float v = b[g * EPG + j];
                if (v > m1) { m2 = m1; m1 = v; }
                else if (v > m2) { m2 = v; }
            }
            gs[g] = m1 + m2;
        }
        int bg = (gs[1] > gs[0]) ? 1 : 0;
        float masked[NEXP];
#pragma unroll
        for (int e = 0; e < NEXP; ++e)
            masked[e] = ((e >> 2) == bg) ? b[e] : 0.0f;
        int i0 = 0; float v0 = masked[0];
#pragma unroll
        for (int e = 1; e < NEXP; ++e)
            if (masked[e] > v0) { v0 = masked[e]; i0 = e; }
        int i1 = -1; float v1 = -1e30f;
#pragma unroll
        for (int e = 0; e < NEXP; ++e) {
            if (e == i0) continue;
            if (masked[e] > v1) { v1 = masked[e]; i1 = e; }
        }
        float w0 = s[i0], w1 = s[i1];
        float inv = 1.f / (w0 + w1 + 1e-20f);
        w0 *= inv; w1 *= inv;
        wpair[t * 2 + 0] = w0;
        wpair[t * 2 + 1] = w1;
        topk_ids[t] = i0 | (i1 << 8);
    }
}

// ---------------- build per-expert pair lists (deterministic compaction) ----------------
__global__ __launch_bounds__(256)
void build_lists(const int* __restrict__ topk_ids,
                 int* __restrict__ counts,
                 int* __restrict__ pair_id)
{
    const int e = blockIdx.x;
    const int tid = threadIdx.x;
    const int lane = tid & 63;
    const int wid = tid >> 6;
    __shared__ int wsum[4];
    __shared__ int rb;
    if (tid == 0) rb = 0;
    __syncthreads();

    int* dst = pair_id + e * T_TOK;
    for (int c0 = 0; c0 < T_TOK; c0 += 256) {
        int t = c0 + tid;
        int ids = topk_ids[t];
        bool m0 = (ids & 0xff) == e;
        bool m1 = ((ids >> 8) & 0xff) == e;
        unsigned long long b0 = __ballot(m0);
        unsigned long long b1 = __ballot(m1);
        int n0 = __popcll(b0);
        int n1 = __popcll(b1);
        if (lane == 0) wsum[wid] = n0 + n1;
        __syncthreads();
        int pre = 0, tot = 0;
#pragma unroll
        for (int w = 0; w < 4; ++w) {
            int v = wsum[w];
            if (w < wid) pre += v;
            tot += v;
        }
        int mybase = rb + pre;
        unsigned long long ltmask = (lane == 63) ? ~0ull >> 1 : ((1ull << lane) - 1);
        if (m0) dst[mybase + __popcll(b0 & ltmask)] = t * 2;
        if (m1) dst[mybase + n0 + __popcll(b1 & ltmask)] = t * 2 + 1;
        __syncthreads();
        if (tid == 0) rb += tot;
    }
    __syncthreads();
    if (tid == 0) counts[e] = rb;
}

// ---------------- merged transpose + fp32->bf16 convert ----------------
// gate/up are written INTERLEAVED into wguT: for original col i,
//   gate -> row' = (i>>4)*32 + (i&15), up -> row' + 16.  (16-col group pairing)
__global__ __launch_bounds__(256)
void transpose_all(const float* __restrict__ wg,  const float* __restrict__ wu,
                   const float* __restrict__ wdn, const float* __restrict__ swg,
                   const float* __restrict__ swu, const float* __restrict__ swd,
                   u16* __restrict__ wguT,   // [E][1024][1024]
                   u16* __restrict__ wdnT,   // [E][1024][512]
                   u16* __restrict__ swguT,  // [1024][1024]
                   u16* __restrict__ swdT)   // [1024][512]
{
    const int z = blockIdx.z;
    const float* src; u16* dst; int R, C, mode;   // mode: 0 plain, 1 gate, 2 up
    const size_t EW = (size_t)HDIM * IDIM;
    const size_t GW = (size_t)HDIM * HDIM;
    if (z < 8)       { src = wg  + (size_t)z * EW;        dst = wguT + (size_t)z * GW;        R = HDIM; C = IDIM; mode = 1; }
    else if (z < 16) { src = wu  + (size_t)(z - 8) * EW;  dst = wguT + (size_t)(z - 8) * GW;  R = HDIM; C = IDIM; mode = 2; }
    else if (z < 24) { src = wdn + (size_t)(z - 16) * EW; dst = wdnT + (size_t)(z - 16) * EW; R = IDIM; C = HDIM; mode = 0; }
    else if (z == 24){ src = swg; dst = swguT; R = HDIM; C = IDIM; mode = 1; }
    else if (z == 25){ src = swu; dst = swguT; R = HDIM; C = IDIM; mode = 2; }
    else             { src = swd; dst = swdT;  R = IDIM; C = HDIM; mode = 0; }
    int r0 = blockIdx.x * 64, c0 = blockIdx.y * 64;
    if (r0 >= R || c0 >= C) return;

    __shared__ float tile[64][65];
    int t = threadIdx.x;
    int row = t >> 2;
#pragma unroll
    for (int j = 0; j < 4; ++j) {
        int c = ((t & 3) + j * 4) * 4;
        *(float4*)&tile[row][c] = *(const float4*)(src + (size_t)(r0 + row) * C + c0 + c);
    }
    __syncthreads();
    int c = t >> 2;
    int rchunk = (t & 3) * 16;
    __attribute__((aligned(16))) u16 pack[16];
#pragma unroll
    for (int i = 0; i < 16; ++i)
        pack[i] = f2bf(tile[rchunk + i][c]);
    int i = c0 + c;                       // original column = base output row
    int rowp;
    if (mode == 0) rowp = i;
    else           rowp = ((i >> 4) << 5) + (i & 15) + ((mode == 2) ? 16 : 0);
    uint4* d4 = (uint4*)(dst + (size_t)rowp * R + r0 + rchunk);
    d4[0] = *(uint4*)&pack[0];
    d4[1] = *(uint4*)&pack[8];
}

// ---------------- gateup: 256x256 tile, 8 waves, dbuf + counted vmcnt ----------------
// GEMM: rows x 1024(K) -> 256 interleaved g|u columns; epilogue pairs (2p,2p+1) -> silu(g)*u.
// z=0: shared (Xb -> hs). z=1..8: expert z-1 (gathered Xb -> hp by pair id).
__global__ __launch_bounds__(512, 2)
void gateup_all(const u16* __restrict__ Xb,
                const u16* __restrict__ WguT,  // [E][1024][1024]
                const u16* __restrict__ sWguT, // [1024][1024]
                u16* __restrict__ hs,          // [T,I]
                u16* __restrict__ hp,          // [2T,I]
                const int* __restrict__ counts,
                const int* __restrict__ pair_id)
{
    const int z = blockIdx.z;
    const bool SH = (z == 0);
    const int e = z - 1;
    const int nrows = SH ? T_TOK : counts[e];
    const int bm0 = blockIdx.x * 256;
    if (bm0 >= nrows) return;
    const int bn0 = blockIdx.y * 256;
    const u16* bsrc = SH ? sWguT : WguT + (size_t)e * HDIM * HDIM;
    const int* plist = SH ? nullptr : (pair_id + e * T_TOK);
    u16* hout = SH ? hs : hp;

    __shared__ __attribute__((aligned(16))) short As[2 * 256 * 64];  // 64 KB
    __shared__ __attribute__((aligned(16))) short Bs[2 * 256 * 64];  // 64 KB

    const int tid = threadIdx.x;
    const int lane = tid & 63;
    const int wid = tid >> 6;

    const char* aptr[4]; const char* bptr[4];
#pragma unroll
    for (int i = 0; i < 4; ++i) {
        int g = wid * 4 + i;
        int r = g * 8 + (lane >> 3);               // 0..255
        int row = bm0 + r;
        int srow;
        if (SH) srow = row;
        else    srow = (row < nrows) ? (plist[row] >> 1) : 0;
        int cslot = ((lane & 7) ^ (r & 7)) * 8;
        aptr[i] = (const char*)(Xb + (size_t)srow * HDIM + cslot);
        bptr[i] = (const char*)(bsrc + (size_t)(bn0 + r) * HDIM + cslot);
    }

    auto stage = [&](int buf, int k) {
        size_t ko = (size_t)k * 128;
#pragma unroll
        for (int i = 0; i < 4; ++i) {
            GLD16(aptr[i] + ko, (char*)As + buf * 32768 + (wid * 4 + i) * 1024);
            GLD16(bptr[i] + ko, (char*)Bs + buf * 32768 + (wid * 4 + i) * 1024);
        }
    };

    const int wm = wid >> 2, wn = wid & 3;
    const int m0 = wm * 128, n0 = wn * 64;
    const int lr = lane & 15, lg = lane >> 4;

    f32x4 acc[8][4] = {};

    const int NT = HDIM / 64;   // 16
    stage(0, 0);
    for (int k = 0; k < NT; ++k) {
        int c = k & 1;
        if (k + 1 < NT) {
            stage(c ^ 1, k + 1);
            asm volatile("s_waitcnt vmcnt(8)" ::: "memory");
        } else {
            asm volatile("s_waitcnt vmcnt(0)" ::: "memory");
        }
        __builtin_amdgcn_s_barrier();
        __builtin_amdgcn_sched_barrier(0);
        const char* ab = (const char*)As + c * 32768;
        const char* bb = (const char*)Bs + c * 32768;
#pragma unroll
        for (int kk = 0; kk < 2; ++kk) {
            short8 af[8], bf[4];
#pragma unroll
            for (int mf = 0; mf < 8; ++mf) {
                int row = m0 + mf * 16 + lr;
                int slot = (kk * 4 + lg) ^ (row & 7);
                af[mf] = *(const short8*)(ab + row * 128 + slot * 16);
            }
#pragma unroll
            for (int nf = 0; nf < 4; ++nf) {
                int row = n0 + nf * 16 + lr;
                int slot = (kk * 4 + lg) ^ (row & 7);
                bf[nf] = *(const short8*)(bb + row * 128 + slot * 16);
            }
#pragma unroll
            for (int mf = 0; mf < 8; ++mf)
#pragma unroll
                for (int nf = 0; nf < 4; ++nf)
                    acc[mf][nf] = __builtin_amdgcn_mfma_f32_16x16x32_bf16(af[mf], bf[nf], acc[mf][nf], 0, 0, 0);
        }
        asm volatile("s_waitcnt lgkmcnt(0)" ::: "memory");
        __builtin_amdgcn_sched_barrier(0);
        __builtin_amdgcn_s_barrier();
    }

    // epilogue: pair (2p, 2p+1) = (g, u) for h col = bn0/2 + wn*32 + p*16 + lr
#pragma unroll
    for (int mf = 0; mf < 8; ++mf) {
#pragma unroll
        for (int j = 0; j < 4; ++j) {
            int row = bm0 + m0 + mf * 16 + lg * 4 + j;
            if (row >= nrows) continue;
            int outrow = SH ? row : plist[row];
            u16* dst = hout + (size_t)outrow * IDIM + (bn0 >> 1) + wn * 32 + lr;
#pragma unroll
            for (int p = 0; p < 2; ++p) {
                float gv = acc[mf][2 * p][j], uv = acc[mf][2 * p + 1][j];
                float sg = gv / (1.f + __expf(-gv));
                dst[p * 16] = f2bf(sg * uv);
            }
        }
    }
}

// ---------------- routed down: 256x256, dbuf + counted vmcnt ----------------
// slot0 -> out (fp32, exclusive rows), slot1 -> y1 (bf16)
__global__ __launch_bounds__(512, 2)
void down_routed(const u16* __restrict__ Hp,      // [2T,I]
                 const u16* __restrict__ WdT,     // [E,H,I]
                 float* __restrict__ out,         // [T,H]
                 u16* __restrict__ y1,            // [T,H]
                 const float* __restrict__ wpair,
                 const int* __restrict__ counts,
                 const int* __restrict__ pair_id)
{
    const int e = blockIdx.z;
    const int nrows = counts[e];
    const int bm0 = blockIdx.x * 256;
    if (bm0 >= nrows) return;
    const int bn0 = blockIdx.y * 256;
    const u16* wdT = WdT + (size_t)e * HDIM * IDIM;
    const int* plist = pair_id + e * T_TOK;

    __shared__ __attribute__((aligned(16))) short As[2 * 256 * 64];
    __shared__ __attribute__((aligned(16))) short Bs[2 * 256 * 64];

    const int tid = threadIdx.x;
    const int lane = tid & 63;
    const int wid = tid >> 6;

    const char* aptr[4]; const char* bptr[4];
#pragma unroll
    for (int i = 0; i < 4; ++i) {
        int g = wid * 4 + i;
        int r = g * 8 + (lane >> 3);
        int row = bm0 + r;
        int srow = (row < nrows) ? plist[row] : 0;
        int cslot = ((lane & 7) ^ (r & 7)) * 8;
        aptr[i] = (const char*)(Hp + (size_t)srow * IDIM + cslot);
        bptr[i] = (const char*)(wdT + (size_t)(bn0 + r) * IDIM + cslot);
    }

    auto stage = [&](int buf, int k) {
        size_t ko = (size_t)k * 128;
#pragma unroll
        for (int i = 0; i < 4; ++i) {
            GLD16(aptr[i] + ko, (char*)As + buf * 32768 + (wid * 4 + i) * 1024);
            GLD16(bptr[i] + ko, (char*)Bs + buf * 32768 + (wid * 4 + i) * 1024);
        }
    };

    const int wm = wid >> 2, wn = wid & 3;
    const int m0 = wm * 128, n0 = wn * 64;
    const int lr = lane & 15, lg = lane >> 4;

    f32x4 acc[8][4] = {};

    const int NT = IDIM / 64;   // 8
    stage(0, 0);
    for (int k = 0; k < NT; ++k) {
        int c = k & 1;
        if (k + 1 < NT) {
            stage(c ^ 1, k + 1);
            asm volatile("s_waitcnt vmcnt(8)" ::: "memory");
        } else {
            asm volatile("s_waitcnt vmcnt(0)" ::: "memory");
        }
        __builtin_amdgcn_s_barrier();
        __builtin_amdgcn_sched_barrier(0);
        const char* ab = (const char*)As + c * 32768;
        const char* bb = (const char*)Bs + c * 32768;
#pragma unroll
        for (int kk = 0; kk < 2; ++kk) {
            short8 af[8], bf[4];
#pragma unroll
            for (int mf = 0; mf < 8; ++mf) {
                int row = m0 + mf * 16 + lr;
                int slot = (kk * 4 + lg) ^ (row & 7);
                af[mf] = *(const short8*)(ab + row * 128 + slot * 16);
            }
#pragma unroll
            for (int nf = 0; nf < 4; ++nf) {
                int row = n0 + nf * 16 + lr;
                int slot = (kk * 4 + lg) ^ (row & 7);
                bf[nf] = *(const short8*)(bb + row * 128 + slot * 16);
            }
#pragma unroll
            for (int mf = 0; mf < 8; ++mf)
#pragma unroll
                for (int nf = 0; nf < 4; ++nf)
                    acc[mf][nf] = __builtin_amdgcn_mfma_f32_16x16x32_bf16(af[mf], bf[nf], acc[mf][nf], 0, 0, 0);
        }
        asm volatile("s_waitcnt lgkmcnt(0)" ::: "memory");
        __builtin_amdgcn_sched_barrier(0);
        __builtin_amdgcn_s_barrier();
    }

#pragma unroll
    for (int mf = 0; mf < 8; ++mf) {
#pragma unroll
        for (int j = 0; j < 4; ++j) {
            int row = bm0 + m0 + mf * 16 + lg * 4 + j;
            if (row >= nrows) continue;
            int p = plist[row];
            int t = p >> 1;
            float w = wpair[p];
            if ((p & 1) == 0) {
                float* dst = out + (size_t)t * HDIM + bn0 + n0 + lr;
#pragma unroll
                for (int nf = 0; nf < 4; ++nf)
                    dst[nf * 16] = acc[mf][nf][j] * w;
            } else {
                u16* dst = y1 + (size_t)t * HDIM + bn0 + n0 + lr;
#pragma unroll
                for (int nf = 0; nf < 4; ++nf)
                    dst[nf * 16] = f2bf(acc[mf][nf][j] * w);
            }
        }
    }
}

// ---------------- shared down + combine: out = out(slot0) + y1(slot1) + hs@swd ----------------
__global__ __launch_bounds__(512, 2)
void down_shared_combine(const u16* __restrict__ Hs,   // [T,I]
                         const u16* __restrict__ swdT, // [H,I]
                         const u16* __restrict__ y1,   // [T,H]
                         float* __restrict__ out)      // [T,H]
{
    const int bm0 = blockIdx.x * 256;
    const int bn0 = blockIdx.y * 256;

    __shared__ __attribute__((aligned(16))) short As[2 * 256 * 64];
    __shared__ __attribute__((aligned(16))) short Bs[2 * 256 * 64];

    const int tid = threadIdx.x;
    const int lane = tid & 63;
    const int wid = tid >> 6;

    const char* aptr[4]; const char* bptr[4];
#pragma unroll
    for (int i = 0; i < 4; ++i) {
        int g = wid * 4 + i;
        int r = g * 8 + (lane >> 3);
        int cslot = ((lane & 7) ^ (r & 7)) * 8;
        aptr[i] = (const char*)(Hs + (size_t)(bm0 + r) * IDIM + cslot);
        bptr[i] = (const char*)(swdT + (size_t)(bn0 + r) * IDIM + cslot);
    }

    auto stage = [&](int buf, int k) {
        size_t ko = (size_t)k * 128;
#pragma unroll
        for (int i = 0; i < 4; ++i) {
            GLD16(aptr[i] + ko, (char*)As + buf * 32768 + (wid * 4 + i) * 1024);
            GLD16(bptr[i] + ko, (char*)Bs + buf * 32768 + (wid * 4 + i) * 1024);
        }
    };

    const int wm = wid >> 2, wn = wid & 3;
    const int m0 = wm * 128, n0 = wn * 64;
    const int lr = lane & 15, lg = lane >> 4;

    f32x4 acc[8][4] = {};

    const int NT = IDIM / 64;   // 8
    stage(0, 0);
    for (int k = 0; k < NT; ++k) {
        int c = k & 1;
        if (k + 1 < NT) {
            stage(c ^ 1, k + 1);
            asm volatile("s_waitcnt vmcnt(8)" ::: "memory");
        } else {
            asm volatile("s_waitcnt vmcnt(0)" ::: "memory");
        }
        __builtin_amdgcn_s_barrier();
        __builtin_amdgcn_sched_barrier(0);
        const char* ab = (const char*)As + c * 32768;
        const char* bb = (const char*)Bs + c * 32768;
#pragma unroll
        for (int kk = 0; kk < 2; ++kk) {
            short8 af[8], bf[4];
#pragma unroll
            for (int mf = 0; mf < 8; ++mf) {
                int row = m0 + mf * 16 + lr;
                int slot = (kk * 4 + lg) ^ (row & 7);
                af[mf] = *(const short8*)(ab + row * 128 + slot * 16);
            }
#pragma unroll
            for (int nf = 0; nf < 4; ++nf) {
                int row = n0 + nf * 16 + lr;
                int slot = (kk * 4 + lg) ^ (row & 7);
                bf[nf] = *(const short8*)(bb + row * 128 + slot * 16);
            }
#pragma unroll
            for (int mf = 0; mf < 8; ++mf)
#pragma unroll
                for (int nf = 0; nf < 4; ++nf)
                    acc[mf][nf] = __builtin_amdgcn_mfma_f32_16x16x32_bf16(af[mf], bf[nf], acc[mf][nf], 0, 0, 0);
        }
        asm volatile("s_waitcnt lgkmcnt(0)" ::: "memory");
        __builtin_amdgcn_sched_barrier(0);
        __builtin_amdgcn_s_barrier();
    }

#pragma unroll
    for (int mf = 0; mf < 8; ++mf) {
#pragma unroll
        for (int j = 0; j < 4; ++j) {
            int t = bm0 + m0 + mf * 16 + lg * 4 + j;
            float* dst = out + (size_t)t * HDIM + bn0 + n0 + lr;
            const u16* ysrc = y1 + (size_t)t * HDIM + bn0 + n0 + lr;
#pragma unroll
            for (int nf = 0; nf < 4; ++nf) {
                float prev = dst[nf * 16];                  // slot0 contribution
                float yv = bf2f(ysrc[nf * 16]);             // slot1 contribution
                dst[nf * 16] = prev + yv + acc[mf][nf][j];
            }
        }
    }
}

extern "C" void kernel_launch(void* const* d_in, const int* in_sizes, int n_in,
                              void* d_out, int out_size, void* d_ws, size_t ws_size,
                              hipStream_t stream) {
    const float* X    = (const float*)d_in[0];
    const float* Wr   = (const float*)d_in[1];
    const float* bias = (const float*)d_in[2];
    const float* wg   = (const float*)d_in[3];
    const float* wu   = (const float*)d_in[4];
    const float* wdn  = (const float*)d_in[5];
    const float* swg  = (const float*)d_in[6];
    const float* swu  = (const float*)d_in[7];
    const float* swd  = (const float*)d_in[8];
    float* out = (float*)d_out;
    (void)in_sizes; (void)n_in; (void)out_size; (void)ws_size;

    char* ws = (char*)d_ws;
    const size_t MB = 1048576;
    int*   counts   = (int*)ws;                          // 32 B
    float* wpair    = (float*)(ws + 4096);               // 64 KB
    int*   pair_id  = (int*)(ws + 4096 + 65536);         // 256 KB
    int*   topk_ids = (int*)(ws + 524288);               // 32 KB
    u16* Xb    = (u16*)(ws + 1 * MB);                    // 16 MB [T,H]; reused as y1 after gateup
    u16* wguT  = (u16*)(ws + 17 * MB);                   // 16 MB [E][1024][1024] interleaved g|u
    u16* wdnT  = (u16*)(ws + 33 * MB);                   // 8 MB  [E][1024][512]
    u16* swguT = (u16*)(ws + 41 * MB);                   // 2 MB  [1024][1024]
    u16* swdT  = (u16*)(ws + 43 * MB);                   // 1 MB  [1024][512]
    u16* hs    = (u16*)(ws + 44 * MB);                   // 8 MB  [T,I]
    u16* hp    = (u16*)(ws + 52 * MB);                   // 16 MB [2T,I]
    u16* y1    = Xb;                                     // alias: Xb dead after gateup_all

    router_kernel<<<T_TOK / 4, 256, 0, stream>>>(X, Wr, bias, Xb, wpair, topk_ids);
    build_lists<<<NEXP, 256, 0, stream>>>(topk_ids, counts, pair_id);
    transpose_all<<<dim3(16, 16, 27), 256, 0, stream>>>(
        wg, wu, wdn, swg, swu, swd, wguT, wdnT, swguT, swdT);

    // merged gateup: z=0 shared -> hs, z=1..8 routed -> hp   (N' = 1024 interleaved)
    gateup_all<<<dim3(T_TOK / 256, HDIM / 256, NEXP + 1), 512, 0, stream>>>(
        Xb, wguT, swguT, hs, hp, counts, pair_id);

    // routed down: slot0 -> out (exclusive rows), slot1 -> y1
    down_routed<<<dim3(T_TOK / 256, HDIM / 256, NEXP), 512, 0, stream>>>(
        hp, wdnT, out, y1, wpair, counts, pair_id);

    // shared down fused with combine
    down_shared_combine<<<dim3(T_TOK / 256, HDIM / 256, 1), 512, 0, stream>>>(
        hs, swdT, y1, out);
}

// Round 8
// 267.100 us; speedup vs baseline: 1.4275x; 1.4275x over previous
//
#include <hip/hip_runtime.h>
#include <math.h>
#include <stdint.h>

#define T_TOK 8192
#define HDIM 1024
#define IDIM 512
#define NEXP 8
#define NGRP 2
#define EPG 4

typedef unsigned short u16;
typedef __attribute__((ext_vector_type(8))) short short8;   // 8 bf16 in 4 VGPRs
typedef __attribute__((ext_vector_type(4))) float f32x4;

// async global->LDS, 16B per lane; LDS dest is wave-uniform base (HW adds lane*16)
#define GLD16(gp, lp) __builtin_amdgcn_global_load_lds(                        \
    (const __attribute__((address_space(1))) unsigned int*)(gp),               \
    (__attribute__((address_space(3))) unsigned int*)(lp), 16, 0, 0)

__device__ __forceinline__ u16 f2bf(float f) {  // RNE float->bf16
    unsigned int u = __float_as_uint(f);
    u += 0x7fffu + ((u >> 16) & 1u);
    return (u16)(u >> 16);
}
__device__ __forceinline__ float bf2f(u16 v) {
    return __uint_as_float(((unsigned int)v) << 16);
}

// ---------------- router: one wave per token; no atomics ----------------
__global__ __launch_bounds__(256)
void router_kernel(const float* __restrict__ X,
                   const float* __restrict__ Wr,    // [E,H]
                   const float* __restrict__ bias,  // [E]
                   u16* __restrict__ Xb,            // [T,H] bf16 out
                   float* __restrict__ wpair,       // [2T]
                   int* __restrict__ topk_ids)      // [T] packed i0 | i1<<8
{
    int wave = threadIdx.x >> 6;
    int lane = threadIdx.x & 63;
    int t = blockIdx.x * 4 + wave;
    if (t >= T_TOK) return;

    float acc[NEXP];
#pragma unroll
    for (int e = 0; e < NEXP; ++e) acc[e] = 0.f;

    const float4* X4 = (const float4*)(X + (size_t)t * HDIM);
#pragma unroll
    for (int jj = 0; jj < 4; ++jj) {
        float4 xv = X4[lane + jj * 64];
        ushort4 bv;
        bv.x = f2bf(xv.x); bv.y = f2bf(xv.y); bv.z = f2bf(xv.z); bv.w = f2bf(xv.w);
        *(ushort4*)(Xb + (size_t)t * HDIM + (size_t)(lane + jj * 64) * 4) = bv;
#pragma unroll
        for (int e = 0; e < NEXP; ++e) {
            const float4* W4 = (const float4*)(Wr + (size_t)e * HDIM);
            float4 wv = W4[lane + jj * 64];
            acc[e] += xv.x * wv.x + xv.y * wv.y + xv.z * wv.z + xv.w * wv.w;
        }
    }
#pragma unroll
    for (int e = 0; e < NEXP; ++e) {
#pragma unroll
        for (int off = 32; off >= 1; off >>= 1)
            acc[e] += __shfl_xor(acc[e], off, 64);
    }

    if (lane == 0) {
        float s[NEXP], b[NEXP];
#pragma unroll
        for (int e = 0; e < NEXP; ++e) {
            s[e] = 1.f / (1.f + expf(-acc[e]));
            b[e] = s[e] + bias[e];
        }
        float gs[NGRP];
#pragma unroll
        for (int g = 0; g < NGRP; ++g) {
            float m1 = -1e30f, m2 = -1e30f;
#pragma unroll
            for (int j = 0; j < EPG; ++j) {
                float v = b[g * EPG + j];
                if (v > m1) { m2 = m1; m1 = v; }
                else if (v > m2) { m2 = v; }
            }
            gs[g] = m1 + m2;
        }
        int bg = (gs[1] > gs[0]) ? 1 : 0;
        float masked[NEXP];
#pragma unroll
        for (int e = 0; e < NEXP; ++e)
            masked[e] = ((e >> 2) == bg) ? b[e] : 0.0f;
        int i0 = 0; float v0 = masked[0];
#pragma unroll
        for (int e = 1; e < NEXP; ++e)
            if (masked[e] > v0) { v0 = masked[e]; i0 = e; }
        int i1 = -1; float v1 = -1e30f;
#pragma unroll
        for (int e = 0; e < NEXP; ++e) {
            if (e == i0) continue;
            if (masked[e] > v1) { v1 = masked[e]; i1 = e; }
        }
        float w0 = s[i0], w1 = s[i1];
        float inv = 1.f / (w0 + w1 + 1e-20f);
        w0 *= inv; w1 *= inv;
        wpair[t * 2 + 0] = w0;
        wpair[t * 2 + 1] = w1;
        topk_ids[t] = i0 | (i1 << 8);
    }
}

// ---------------- build per-expert pair lists (deterministic compaction) ----------------
__global__ __launch_bounds__(256)
void build_lists(const int* __restrict__ topk_ids,
                 int* __restrict__ counts,
                 int* __restrict__ pair_id)
{
    const int e = blockIdx.x;
    const int tid = threadIdx.x;
    const int lane = tid & 63;
    const int wid = tid >> 6;
    __shared__ int wsum[4];
    __shared__ int rb;
    if (tid == 0) rb = 0;
    __syncthreads();

    int* dst = pair_id + e * T_TOK;
    for (int c0 = 0; c0 < T_TOK; c0 += 256) {
        int t = c0 + tid;
        int ids = topk_ids[t];
        bool m0 = (ids & 0xff) == e;
        bool m1 = ((ids >> 8) & 0xff) == e;
        unsigned long long b0 = __ballot(m0);
        unsigned long long b1 = __ballot(m1);
        int n0 = __popcll(b0);
        int n1 = __popcll(b1);
        if (lane == 0) wsum[wid] = n0 + n1;
        __syncthreads();
        int pre = 0, tot = 0;
#pragma unroll
        for (int w = 0; w < 4; ++w) {
            int v = wsum[w];
            if (w < wid) pre += v;
            tot += v;
        }
        int mybase = rb + pre;
        unsigned long long ltmask = (lane == 63) ? ~0ull >> 1 : ((1ull << lane) - 1);
        if (m0) dst[mybase + __popcll(b0 & ltmask)] = t * 2;
        if (m1) dst[mybase + n0 + __popcll(b1 & ltmask)] = t * 2 + 1;
        __syncthreads();
        if (tid == 0) rb += tot;
    }
    __syncthreads();
    if (tid == 0) counts[e] = rb;
}

// ---------------- merged transpose + fp32->bf16 convert ----------------
__global__ __launch_bounds__(256)
void transpose_all(const float* __restrict__ wg,  const float* __restrict__ wu,
                   const float* __restrict__ wdn, const float* __restrict__ swg,
                   const float* __restrict__ swu, const float* __restrict__ swd,
                   u16* __restrict__ wgT, u16* __restrict__ wuT, u16* __restrict__ wdnT,
                   u16* __restrict__ swgT, u16* __restrict__ swuT, u16* __restrict__ swdT)
{
    const int z = blockIdx.z;
    const float* src; u16* dst; int R, C;
    const size_t EW = (size_t)HDIM * IDIM;
    if (z < 8)       { src = wg  + (size_t)z * EW;        dst = wgT  + (size_t)z * EW;        R = HDIM; C = IDIM; }
    else if (z < 16) { src = wu  + (size_t)(z - 8) * EW;  dst = wuT  + (size_t)(z - 8) * EW;  R = HDIM; C = IDIM; }
    else if (z < 24) { src = wdn + (size_t)(z - 16) * EW; dst = wdnT + (size_t)(z - 16) * EW; R = IDIM; C = HDIM; }
    else if (z == 24){ src = swg; dst = swgT; R = HDIM; C = IDIM; }
    else if (z == 25){ src = swu; dst = swuT; R = HDIM; C = IDIM; }
    else             { src = swd; dst = swdT; R = IDIM; C = HDIM; }
    int r0 = blockIdx.x * 64, c0 = blockIdx.y * 64;
    if (r0 >= R || c0 >= C) return;

    __shared__ float tile[64][65];
    int t = threadIdx.x;
    int row = t >> 2;
#pragma unroll
    for (int j = 0; j < 4; ++j) {
        int c = ((t & 3) + j * 4) * 4;
        *(float4*)&tile[row][c] = *(const float4*)(src + (size_t)(r0 + row) * C + c0 + c);
    }
    __syncthreads();
    int c = t >> 2;
    int rchunk = (t & 3) * 16;
    __attribute__((aligned(16))) u16 pack[16];
#pragma unroll
    for (int i = 0; i < 16; ++i)
        pack[i] = f2bf(tile[rchunk + i][c]);
    uint4* d4 = (uint4*)(dst + (size_t)(c0 + c) * R + r0 + rchunk);
    d4[0] = *(uint4*)&pack[0];
    d4[1] = *(uint4*)&pack[8];
}

// ---------------- merged gate/up MFMA GEMM + SiLU -> h (bf16) ----------------
// 128x64(x2) tile, BK=64, T3-minimum schedule: 2 LDS buffers, stage-next first,
// ONE vmcnt(0)+barrier per K-tile AFTER the MFMA cluster. Swizzle identical to r6 (0 conflicts).
__global__ __launch_bounds__(256)
void gateup_all(const u16* __restrict__ Xb,
                const u16* __restrict__ WgT, const u16* __restrict__ WuT,     // [E,I,H]
                const u16* __restrict__ sWgT, const u16* __restrict__ sWuT,   // [I,H]
                u16* __restrict__ hs,   // [T,I]
                u16* __restrict__ hp,   // [2T,I]
                const int* __restrict__ counts,
                const int* __restrict__ pair_id)
{
    const int z = blockIdx.z;
    const bool SH = (z == 0);
    const int e = z - 1;
    const int nrows = SH ? T_TOK : counts[e];
    const int bm0 = blockIdx.x * 128;
    if (bm0 >= nrows) return;
    const int bn0 = blockIdx.y * 64;
    const u16* wgT = SH ? sWgT : WgT + (size_t)e * HDIM * IDIM;
    const u16* wuT = SH ? sWuT : WuT + (size_t)e * HDIM * IDIM;
    const int* plist = SH ? nullptr : (pair_id + e * T_TOK);
    u16* hout = SH ? hs : hp;

    __shared__ __attribute__((aligned(16))) short As[2 * 128 * 64];  // 32 KB
    __shared__ __attribute__((aligned(16))) short Bg[2 * 64 * 64];   // 16 KB
    __shared__ __attribute__((aligned(16))) short Bu[2 * 64 * 64];   // 16 KB

    const int tid = threadIdx.x;
    const int lane = tid & 63;
    const int wid = tid >> 6;

    // staging: pre-swizzled global source, linear LDS dest (both-sides swizzle)
    const char* aptr[4];
#pragma unroll
    for (int i = 0; i < 4; ++i) {
        int r = (wid * 4 + i) * 8 + (lane >> 3);
        int row = bm0 + r;
        int srow;
        if (SH) srow = row;
        else    srow = (row < nrows) ? (plist[row] >> 1) : 0;
        int cslot = ((lane & 7) ^ (r & 7)) * 8;
        aptr[i] = (const char*)(Xb + (size_t)srow * HDIM + cslot);
    }
    const char* bgptr[2]; const char* buptr[2];
#pragma unroll
    for (int i = 0; i < 2; ++i) {
        int r = (wid * 2 + i) * 8 + (lane >> 3);
        int nn = bn0 + r;
        int cslot = ((lane & 7) ^ (r & 7)) * 8;
        bgptr[i] = (const char*)(wgT + (size_t)nn * HDIM + cslot);
        buptr[i] = (const char*)(wuT + (size_t)nn * HDIM + cslot);
    }

    auto stage = [&](int buf) {
#pragma unroll
        for (int i = 0; i < 4; ++i) {
            GLD16(aptr[i], (char*)As + buf * 16384 + (wid * 4 + i) * 1024);
            aptr[i] += 128;
        }
#pragma unroll
        for (int i = 0; i < 2; ++i) {
            GLD16(bgptr[i], (char*)Bg + buf * 8192 + (wid * 2 + i) * 1024);
            GLD16(buptr[i], (char*)Bu + buf * 8192 + (wid * 2 + i) * 1024);
            bgptr[i] += 128; buptr[i] += 128;
        }
    };

    const int wm = wid >> 1, wn = wid & 1;
    const int m0 = wm * 64, n0 = wn * 32;
    const int lr = lane & 15, lg = lane >> 4;

    f32x4 accg[4][2] = {};
    f32x4 accu[4][2] = {};

    const int NT = HDIM / 64;   // 16
    stage(0);
    asm volatile("s_waitcnt vmcnt(0)" ::: "memory");
    __builtin_amdgcn_s_barrier();
    int cur = 0;
    for (int t = 0; t < NT; ++t) {
        if (t < NT - 1) stage(cur ^ 1);     // prefetch flies under this tile's compute
        const char* ab = (const char*)As + cur * 16384;
        const char* gb = (const char*)Bg + cur * 8192;
        const char* ub = (const char*)Bu + cur * 8192;
#pragma unroll
        for (int kk = 0; kk < 2; ++kk) {
            short8 af[4], bgf[2], buf_[2];
#pragma unroll
            for (int mf = 0; mf < 4; ++mf) {
                int row = m0 + mf * 16 + lr;
                int slot = (kk * 4 + lg) ^ (row & 7);
                af[mf] = *(const short8*)(ab + row * 128 + slot * 16);
            }
#pragma unroll
            for (int nf = 0; nf < 2; ++nf) {
                int row = n0 + nf * 16 + lr;
                int slot = (kk * 4 + lg) ^ (row & 7);
                bgf[nf]  = *(const short8*)(gb + row * 128 + slot * 16);
                buf_[nf] = *(const short8*)(ub + row * 128 + slot * 16);
            }
            asm volatile("s_waitcnt lgkmcnt(0)" ::: "memory");
            __builtin_amdgcn_s_setprio(1);
#pragma unroll
            for (int mf = 0; mf < 4; ++mf)
#pragma unroll
                for (int nf = 0; nf < 2; ++nf) {
                    accg[mf][nf] = __builtin_amdgcn_mfma_f32_16x16x32_bf16(af[mf], bgf[nf],  accg[mf][nf], 0, 0, 0);
                    accu[mf][nf] = __builtin_amdgcn_mfma_f32_16x16x32_bf16(af[mf], buf_[nf], accu[mf][nf], 0, 0, 0);
                }
            __builtin_amdgcn_s_setprio(0);
        }
        if (t < NT - 1) {
            asm volatile("s_waitcnt vmcnt(0)" ::: "memory");   // next tile landed
            __builtin_amdgcn_s_barrier();                      // also: all reads of cur done
            cur ^= 1;
        }
    }

    // epilogue: C/D layout col=lane&15, row=4*(lane>>4)+reg
#pragma unroll
    for (int mf = 0; mf < 4; ++mf) {
#pragma unroll
        for (int j = 0; j < 4; ++j) {
            int row = bm0 + m0 + mf * 16 + lg * 4 + j;
            if (row >= nrows) continue;
            int outrow = SH ? row : plist[row];
            u16* dst = hout + (size_t)outrow * IDIM + bn0 + n0 + lr;
#pragma unroll
            for (int nf = 0; nf < 2; ++nf) {
                float g = accg[mf][nf][j], u = accu[mf][nf][j];
                float sg = g / (1.f + __expf(-g));
                dst[nf * 16] = f2bf(sg * u);
            }
        }
    }
}

// ---------------- routed down: slot0 -> out (fp32, exclusive rows), slot1 -> y1 (bf16) ----------------
__global__ __launch_bounds__(256)
void down_routed(const u16* __restrict__ Hp,      // [2T,I]
                 const u16* __restrict__ WdT,     // [E,H,I]
                 float* __restrict__ out,         // [T,H]
                 u16* __restrict__ y1,            // [T,H]
                 const float* __restrict__ wpair,
                 const int* __restrict__ counts,
                 const int* __restrict__ pair_id)
{
    const int e = blockIdx.z;
    const int nrows = counts[e];
    const int bm0 = blockIdx.x * 128;
    if (bm0 >= nrows) return;
    const int bn0 = blockIdx.y * 128;
    const u16* wdT = WdT + (size_t)e * HDIM * IDIM;
    const int* plist = pair_id + e * T_TOK;

    __shared__ __attribute__((aligned(16))) short As[2 * 128 * 64];  // 32 KB
    __shared__ __attribute__((aligned(16))) short Bs[2 * 128 * 64];  // 32 KB

    const int tid = threadIdx.x;
    const int lane = tid & 63;
    const int wid = tid >> 6;

    const char* aptr[4];
#pragma unroll
    for (int i = 0; i < 4; ++i) {
        int r = (wid * 4 + i) * 8 + (lane >> 3);
        int row = bm0 + r;
        int srow = (row < nrows) ? plist[row] : 0;
        int cslot = ((lane & 7) ^ (r & 7)) * 8;
        aptr[i] = (const char*)(Hp + (size_t)srow * IDIM + cslot);
    }
    const char* bptr[4];
#pragma unroll
    for (int i = 0; i < 4; ++i) {
        int r = (wid * 4 + i) * 8 + (lane >> 3);
        int cslot = ((lane & 7) ^ (r & 7)) * 8;
        bptr[i] = (const char*)(wdT + (size_t)(bn0 + r) * IDIM + cslot);
    }

    auto stage = [&](int buf) {
#pragma unroll
        for (int i = 0; i < 4; ++i) {
            GLD16(aptr[i], (char*)As + buf * 16384 + (wid * 4 + i) * 1024);
            GLD16(bptr[i], (char*)Bs + buf * 16384 + (wid * 4 + i) * 1024);
            aptr[i] += 128; bptr[i] += 128;
        }
    };

    const int wm = wid >> 1, wn = wid & 1;
    const int m0 = wm * 64, n0 = wn * 64;
    const int lr = lane & 15, lg = lane >> 4;

    f32x4 acc[4][4] = {};

    const int NT = IDIM / 64;   // 8
    stage(0);
    asm volatile("s_waitcnt vmcnt(0)" ::: "memory");
    __builtin_amdgcn_s_barrier();
    int cur = 0;
    for (int t = 0; t < NT; ++t) {
        if (t < NT - 1) stage(cur ^ 1);
        const char* ab = (const char*)As + cur * 16384;
        const char* bb = (const char*)Bs + cur * 16384;
#pragma unroll
        for (int kk = 0; kk < 2; ++kk) {
            short8 af[4], bf[4];
#pragma unroll
            for (int mf = 0; mf < 4; ++mf) {
                int row = m0 + mf * 16 + lr;
                int slot = (kk * 4 + lg) ^ (row & 7);
                af[mf] = *(const short8*)(ab + row * 128 + slot * 16);
            }
#pragma unroll
            for (int nf = 0; nf < 4; ++nf) {
                int row = n0 + nf * 16 + lr;
                int slot = (kk * 4 + lg) ^ (row & 7);
                bf[nf] = *(const short8*)(bb + row * 128 + slot * 16);
            }
            asm volatile("s_waitcnt lgkmcnt(0)" ::: "memory");
            __builtin_amdgcn_s_setprio(1);
#pragma unroll
            for (int mf = 0; mf < 4; ++mf)
#pragma unroll
                for (int nf = 0; nf < 4; ++nf)
                    acc[mf][nf] = __builtin_amdgcn_mfma_f32_16x16x32_bf16(af[mf], bf[nf], acc[mf][nf], 0, 0, 0);
            __builtin_amdgcn_s_setprio(0);
        }
        if (t < NT - 1) {
            asm volatile("s_waitcnt vmcnt(0)" ::: "memory");
            __builtin_amdgcn_s_barrier();
            cur ^= 1;
        }
    }

#pragma unroll
    for (int mf = 0; mf < 4; ++mf) {
#pragma unroll
        for (int j = 0; j < 4; ++j) {
            int row = bm0 + m0 + mf * 16 + lg * 4 + j;
            if (row >= nrows) continue;
            int p = plist[row];
            int t = p >> 1;
            float w = wpair[p];
            if ((p & 1) == 0) {
                float* dst = out + (size_t)t * HDIM + bn0 + n0 + lr;
#pragma unroll
                for (int nf = 0; nf < 4; ++nf)
                    dst[nf * 16] = acc[mf][nf][j] * w;
            } else {
                u16* dst = y1 + (size_t)t * HDIM + bn0 + n0 + lr;
#pragma unroll
                for (int nf = 0; nf < 4; ++nf)
                    dst[nf * 16] = f2bf(acc[mf][nf][j] * w);
            }
        }
    }
}

// ---------------- shared down + combine: out = out(slot0) + y1(slot1) + hs@swd ----------------
__global__ __launch_bounds__(256)
void down_shared_combine(const u16* __restrict__ Hs,   // [T,I]
                         const u16* __restrict__ swdT, // [H,I]
                         const u16* __restrict__ y1,   // [T,H]
                         float* __restrict__ out)      // [T,H]
{
    const int bm0 = blockIdx.x * 128;
    const int bn0 = blockIdx.y * 128;

    __shared__ __attribute__((aligned(16))) short As[2 * 128 * 64];
    __shared__ __attribute__((aligned(16))) short Bs[2 * 128 * 64];

    const int tid = threadIdx.x;
    const int lane = tid & 63;
    const int wid = tid >> 6;

    const char* aptr[4];
#pragma unroll
    for (int i = 0; i < 4; ++i) {
        int r = (wid * 4 + i) * 8 + (lane >> 3);
        int cslot = ((lane & 7) ^ (r & 7)) * 8;
        aptr[i] = (const char*)(Hs + (size_t)(bm0 + r) * IDIM + cslot);
    }
    const char* bptr[4];
#pragma unroll
    for (int i = 0; i < 4; ++i) {
        int r = (wid * 4 + i) * 8 + (lane >> 3);
        int cslot = ((lane & 7) ^ (r & 7)) * 8;
        bptr[i] = (const char*)(swdT + (size_t)(bn0 + r) * IDIM + cslot);
    }

    auto stage = [&](int buf) {
#pragma unroll
        for (int i = 0; i < 4; ++i) {
            GLD16(aptr[i], (char*)As + buf * 16384 + (wid * 4 + i) * 1024);
            GLD16(bptr[i], (char*)Bs + buf * 16384 + (wid * 4 + i) * 1024);
            aptr[i] += 128; bptr[i] += 128;
        }
    };

    const int wm = wid >> 1, wn = wid & 1;
    const int m0 = wm * 64, n0 = wn * 64;
    const int lr = lane & 15, lg = lane >> 4;

    f32x4 acc[4][4] = {};

    const int NT = IDIM / 64;   // 8
    stage(0);
    asm volatile("s_waitcnt vmcnt(0)" ::: "memory");
    __builtin_amdgcn_s_barrier();
    int cur = 0;
    for (int t = 0; t < NT; ++t) {
        if (t < NT - 1) stage(cur ^ 1);
        const char* ab = (const char*)As + cur * 16384;
        const char* bb = (const char*)Bs + cur * 16384;
#pragma unroll
        for (int kk = 0; kk < 2; ++kk) {
            short8 af[4], bf[4];
#pragma unroll
            for (int mf = 0; mf < 4; ++mf) {
                int row = m0 + mf * 16 + lr;
                int slot = (kk * 4 + lg) ^ (row & 7);
                af[mf] = *(const short8*)(ab + row * 128 + slot * 16);
            }
#pragma unroll
            for (int nf = 0; nf < 4; ++nf) {
                int row = n0 + nf * 16 + lr;
                int slot = (kk * 4 + lg) ^ (row & 7);
                bf[nf] = *(const short8*)(bb + row * 128 + slot * 16);
            }
            asm volatile("s_waitcnt lgkmcnt(0)" ::: "memory");
            __builtin_amdgcn_s_setprio(1);
#pragma unroll
            for (int mf = 0; mf < 4; ++mf)
#pragma unroll
                for (int nf = 0; nf < 4; ++nf)
                    acc[mf][nf] = __builtin_amdgcn_mfma_f32_16x16x32_bf16(af[mf], bf[nf], acc[mf][nf], 0, 0, 0);
            __builtin_amdgcn_s_setprio(0);
        }
        if (t < NT - 1) {
            asm volatile("s_waitcnt vmcnt(0)" ::: "memory");
            __builtin_amdgcn_s_barrier();
            cur ^= 1;
        }
    }

#pragma unroll
    for (int mf = 0; mf < 4; ++mf) {
#pragma unroll
        for (int j = 0; j < 4; ++j) {
            int t = bm0 + m0 + mf * 16 + lg * 4 + j;
            float* dst = out + (size_t)t * HDIM + bn0 + n0 + lr;
            const u16* ysrc = y1 + (size_t)t * HDIM + bn0 + n0 + lr;
#pragma unroll
            for (int nf = 0; nf < 4; ++nf) {
                float prev = dst[nf * 16];                  // slot0 contribution
                float yv = bf2f(ysrc[nf * 16]);             // slot1 contribution
                dst[nf * 16] = prev + yv + acc[mf][nf][j];
            }
        }
    }
}

extern "C" void kernel_launch(void* const* d_in, const int* in_sizes, int n_in,
                              void* d_out, int out_size, void* d_ws, size_t ws_size,
                              hipStream_t stream) {
    const float* X    = (const float*)d_in[0];
    const float* Wr   = (const float*)d_in[1];
    const float* bias = (const float*)d_in[2];
    const float* wg   = (const float*)d_in[3];
    const float* wu   = (const float*)d_in[4];
    const float* wdn  = (const float*)d_in[5];
    const float* swg  = (const float*)d_in[6];
    const float* swu  = (const float*)d_in[7];
    const float* swd  = (const float*)d_in[8];
    float* out = (float*)d_out;
    (void)in_sizes; (void)n_in; (void)out_size; (void)ws_size;

    char* ws = (char*)d_ws;
    const size_t MB = 1048576;
    int*   counts   = (int*)ws;                          // 32 B
    float* wpair    = (float*)(ws + 4096);               // 64 KB
    int*   pair_id  = (int*)(ws + 4096 + 65536);         // 256 KB
    int*   topk_ids = (int*)(ws + 524288);               // 32 KB
    u16* Xb   = (u16*)(ws + 1 * MB);                     // 16 MB [T,H]; reused as y1 after gateup
    u16* wgT  = (u16*)(ws + 17 * MB);                    // 8 MB [E,I,H]
    u16* wuT  = (u16*)(ws + 25 * MB);                    // 8 MB
    u16* wdnT = (u16*)(ws + 33 * MB);                    // 8 MB [E,H,I]
    u16* swgT = (u16*)(ws + 41 * MB);                    // 1 MB [I,H]
    u16* swuT = (u16*)(ws + 42 * MB);                    // 1 MB
    u16* swdT = (u16*)(ws + 43 * MB);                    // 1 MB [H,I]
    u16* hs   = (u16*)(ws + 44 * MB);                    // 8 MB [T,I]
    u16* hp   = (u16*)(ws + 52 * MB);                    // 16 MB [2T,I]
    u16* y1   = Xb;                                      // alias: Xb dead after gateup_all

    router_kernel<<<T_TOK / 4, 256, 0, stream>>>(X, Wr, bias, Xb, wpair, topk_ids);
    build_lists<<<NEXP, 256, 0, stream>>>(topk_ids, counts, pair_id);
    transpose_all<<<dim3(16, 16, 27), 256, 0, stream>>>(
        wg, wu, wdn, swg, swu, swd, wgT, wuT, wdnT, swgT, swuT, swdT);

    gateup_all<<<dim3(T_TOK / 128, IDIM / 64, NEXP + 1), 256, 0, stream>>>(
        Xb, wgT, wuT, swgT, swuT, hs, hp, counts, pair_id);

    down_routed<<<dim3(T_TOK / 128, HDIM / 128, NEXP), 256, 0, stream>>>(
        hp, wdnT, out, y1, wpair, counts, pair_id);

    down_shared_combine<<<dim3(T_TOK / 128, HDIM / 128, 1), 256, 0, stream>>>(
        hs, swdT, y1, out);
}

// Round 9
// 203.891 us; speedup vs baseline: 1.8700x; 1.3100x over previous
//
#include <hip/hip_runtime.h>
#include <math.h>
#include <stdint.h>

#define T_TOK 8192
#define HDIM 1024
#define IDIM 512
#define NEXP 8
#define NGRP 2
#define EPG 4

typedef unsigned short u16;
typedef __attribute__((ext_vector_type(8))) short short8;   // 8 bf16 in 4 VGPRs
typedef __attribute__((ext_vector_type(4))) float f32x4;

// async global->LDS, 16B per lane; LDS dest is wave-uniform base (HW adds lane*16)
#define GLD16(gp, lp) __builtin_amdgcn_global_load_lds(                        \
    (const __attribute__((address_space(1))) unsigned int*)(gp),               \
    (__attribute__((address_space(3))) unsigned int*)(lp), 16, 0, 0)

__device__ __forceinline__ u16 f2bf(float f) {  // RNE float->bf16
    unsigned int u = __float_as_uint(f);
    u += 0x7fffu + ((u >> 16) & 1u);
    return (u16)(u >> 16);
}
__device__ __forceinline__ float bf2f(u16 v) {
    return __uint_as_float(((unsigned int)v) << 16);
}

// ---------------- prologue: router (blocks 0..2047) + weight transposes (2048..5503) ----------------
__global__ __launch_bounds__(256)
void prologue(const float* __restrict__ X,
              const float* __restrict__ Wr, const float* __restrict__ bias,
              u16* __restrict__ Xb, float* __restrict__ wpair, int* __restrict__ topk_ids,
              const float* __restrict__ wg,  const float* __restrict__ wu,
              const float* __restrict__ wdn, const float* __restrict__ swg,
              const float* __restrict__ swu, const float* __restrict__ swd,
              u16* __restrict__ wgT, u16* __restrict__ wuT, u16* __restrict__ wdnT,
              u16* __restrict__ swgT, u16* __restrict__ swuT, u16* __restrict__ swdT)
{
    __shared__ float tile[64][65];
    const int bid = blockIdx.x;

    if (bid < 2048) {
        // ---- router: one wave per token; no atomics ----
        int wave = threadIdx.x >> 6;
        int lane = threadIdx.x & 63;
        int t = bid * 4 + wave;

        float acc[NEXP];
#pragma unroll
        for (int e = 0; e < NEXP; ++e) acc[e] = 0.f;

        const float4* X4 = (const float4*)(X + (size_t)t * HDIM);
#pragma unroll
        for (int jj = 0; jj < 4; ++jj) {
            float4 xv = X4[lane + jj * 64];
            ushort4 bv;
            bv.x = f2bf(xv.x); bv.y = f2bf(xv.y); bv.z = f2bf(xv.z); bv.w = f2bf(xv.w);
            *(ushort4*)(Xb + (size_t)t * HDIM + (size_t)(lane + jj * 64) * 4) = bv;
#pragma unroll
            for (int e = 0; e < NEXP; ++e) {
                const float4* W4 = (const float4*)(Wr + (size_t)e * HDIM);
                float4 wv = W4[lane + jj * 64];
                acc[e] += xv.x * wv.x + xv.y * wv.y + xv.z * wv.z + xv.w * wv.w;
            }
        }
#pragma unroll
        for (int e = 0; e < NEXP; ++e) {
#pragma unroll
            for (int off = 32; off >= 1; off >>= 1)
                acc[e] += __shfl_xor(acc[e], off, 64);
        }

        if (lane == 0) {
            float s[NEXP], b[NEXP];
#pragma unroll
            for (int e = 0; e < NEXP; ++e) {
                s[e] = 1.f / (1.f + expf(-acc[e]));
                b[e] = s[e] + bias[e];
            }
            float gs[NGRP];
#pragma unroll
            for (int g = 0; g < NGRP; ++g) {
                float m1 = -1e30f, m2 = -1e30f;
#pragma unroll
                for (int j = 0; j < EPG; ++j) {
                    float v = b[g * EPG + j];
                    if (v > m1) { m2 = m1; m1 = v; }
                    else if (v > m2) { m2 = v; }
                }
                gs[g] = m1 + m2;
            }
            int bg = (gs[1] > gs[0]) ? 1 : 0;
            float masked[NEXP];
#pragma unroll
            for (int e = 0; e < NEXP; ++e)
                masked[e] = ((e >> 2) == bg) ? b[e] : 0.0f;
            int i0 = 0; float v0 = masked[0];
#pragma unroll
            for (int e = 1; e < NEXP; ++e)
                if (masked[e] > v0) { v0 = masked[e]; i0 = e; }
            int i1 = -1; float v1 = -1e30f;
#pragma unroll
            for (int e = 0; e < NEXP; ++e) {
                if (e == i0) continue;
                if (masked[e] > v1) { v1 = masked[e]; i1 = e; }
            }
            float w0 = s[i0], w1 = s[i1];
            float inv = 1.f / (w0 + w1 + 1e-20f);
            w0 *= inv; w1 *= inv;
            wpair[t * 2 + 0] = w0;
            wpair[t * 2 + 1] = w1;
            topk_ids[t] = i0 | (i1 << 8);
        }
        return;
    }

    // ---- transpose + fp32->bf16 convert: 27 matrices x 128 blocks ----
    int tb = bid - 2048;
    int m = tb >> 7;        // matrix id 0..26
    int i = tb & 127;
    const float* src; u16* dst; int R, C;
    const size_t EW = (size_t)HDIM * IDIM;
    if (m < 8)       { src = wg  + (size_t)m * EW;        dst = wgT  + (size_t)m * EW;        R = HDIM; C = IDIM; }
    else if (m < 16) { src = wu  + (size_t)(m - 8) * EW;  dst = wuT  + (size_t)(m - 8) * EW;  R = HDIM; C = IDIM; }
    else if (m < 24) { src = wdn + (size_t)(m - 16) * EW; dst = wdnT + (size_t)(m - 16) * EW; R = IDIM; C = HDIM; }
    else if (m == 24){ src = swg; dst = swgT; R = HDIM; C = IDIM; }
    else if (m == 25){ src = swu; dst = swuT; R = HDIM; C = IDIM; }
    else             { src = swd; dst = swdT; R = IDIM; C = HDIM; }
    int r0, c0;
    if (R == HDIM) { r0 = (i & 15) * 64; c0 = (i >> 4) * 64; }   // 16 x 8 blocks
    else           { r0 = (i & 7) * 64;  c0 = (i >> 3) * 64; }   // 8 x 16 blocks

    int t = threadIdx.x;
    int row = t >> 2;
#pragma unroll
    for (int j = 0; j < 4; ++j) {
        int c = ((t & 3) + j * 4) * 4;
        *(float4*)&tile[row][c] = *(const float4*)(src + (size_t)(r0 + row) * C + c0 + c);
    }
    __syncthreads();
    int c = t >> 2;
    int rchunk = (t & 3) * 16;
    __attribute__((aligned(16))) u16 pack[16];
#pragma unroll
    for (int k = 0; k < 16; ++k)
        pack[k] = f2bf(tile[rchunk + k][c]);
    uint4* d4 = (uint4*)(dst + (size_t)(c0 + c) * R + r0 + rchunk);
    d4[0] = *(uint4*)&pack[0];
    d4[1] = *(uint4*)&pack[8];
}

// ---------------- build per-expert pair lists (deterministic compaction) ----------------
__global__ __launch_bounds__(256)
void build_lists(const int* __restrict__ topk_ids,
                 int* __restrict__ counts,
                 int* __restrict__ pair_id)
{
    const int e = blockIdx.x;
    const int tid = threadIdx.x;
    const int lane = tid & 63;
    const int wid = tid >> 6;
    __shared__ int wsum[4];
    __shared__ int rb;
    if (tid == 0) rb = 0;
    __syncthreads();

    int* dst = pair_id + e * T_TOK;
    for (int c0 = 0; c0 < T_TOK; c0 += 256) {
        int t = c0 + tid;
        int ids = topk_ids[t];
        bool m0 = (ids & 0xff) == e;
        bool m1 = ((ids >> 8) & 0xff) == e;
        unsigned long long b0 = __ballot(m0);
        unsigned long long b1 = __ballot(m1);
        int n0 = __popcll(b0);
        int n1 = __popcll(b1);
        if (lane == 0) wsum[wid] = n0 + n1;
        __syncthreads();
        int pre = 0, tot = 0;
#pragma unroll
        for (int w = 0; w < 4; ++w) {
            int v = wsum[w];
            if (w < wid) pre += v;
            tot += v;
        }
        int mybase = rb + pre;
        unsigned long long ltmask = (lane == 63) ? ~0ull >> 1 : ((1ull << lane) - 1);
        if (m0) dst[mybase + __popcll(b0 & ltmask)] = t * 2;
        if (m1) dst[mybase + n0 + __popcll(b1 & ltmask)] = t * 2 + 1;
        __syncthreads();
        if (tid == 0) rb += tot;
    }
    __syncthreads();
    if (tid == 0) counts[e] = rb;
}

// ---------------- merged gate/up MFMA GEMM + SiLU -> h (bf16) ----------------
// m97 structure (r6-proven): BK=64, 32KB LDS single-buffered, XOR-swizzle (0 conflicts).
// Grid roles: blockIdx.x = column block (fastest -> XCD-local weights), .y = row block, .z = expert.
__global__ __launch_bounds__(256)
void gateup_all(const u16* __restrict__ Xb,
                const u16* __restrict__ WgT, const u16* __restrict__ WuT,     // [E,I,H]
                const u16* __restrict__ sWgT, const u16* __restrict__ sWuT,   // [I,H]
                u16* __restrict__ hs,   // [T,I]
                u16* __restrict__ hp,   // [2T,I]
                const int* __restrict__ counts,
                const int* __restrict__ pair_id)
{
    const int z = blockIdx.z;
    const bool SH = (z == 0);
    const int e = z - 1;
    const int nrows = SH ? T_TOK : counts[e];
    const int bm0 = blockIdx.y * 128;
    if (bm0 >= nrows) return;
    const int bn0 = blockIdx.x * 64;
    const u16* wgT = SH ? sWgT : WgT + (size_t)e * HDIM * IDIM;
    const u16* wuT = SH ? sWuT : WuT + (size_t)e * HDIM * IDIM;
    const int* plist = SH ? nullptr : (pair_id + e * T_TOK);
    u16* hout = SH ? hs : hp;

    __shared__ __attribute__((aligned(16))) short As[128 * 64];  // 16 KB
    __shared__ __attribute__((aligned(16))) short Bg[64 * 64];   // 8 KB
    __shared__ __attribute__((aligned(16))) short Bu[64 * 64];   // 8 KB

    const int tid = threadIdx.x;
    const int lane = tid & 63;
    const int wid = tid >> 6;

    const char* aptr[4];
#pragma unroll
    for (int i = 0; i < 4; ++i) {
        int r = (wid * 4 + i) * 8 + (lane >> 3);
        int row = bm0 + r;
        int srow;
        if (SH) srow = row;
        else    srow = (row < nrows) ? (plist[row] >> 1) : 0;
        int cslot = ((lane & 7) ^ (r & 7)) * 8;
        aptr[i] = (const char*)(Xb + (size_t)srow * HDIM + cslot);
    }
    const char* bgptr[2]; const char* buptr[2];
#pragma unroll
    for (int i = 0; i < 2; ++i) {
        int r = (wid * 2 + i) * 8 + (lane >> 3);
        int nn = bn0 + r;
        int cslot = ((lane & 7) ^ (r & 7)) * 8;
        bgptr[i] = (const char*)(wgT + (size_t)nn * HDIM + cslot);
        buptr[i] = (const char*)(wuT + (size_t)nn * HDIM + cslot);
    }

    const int wm = wid >> 1, wn = wid & 1;
    const int m0 = wm * 64, n0 = wn * 32;
    const int lr = lane & 15, lg = lane >> 4;

    f32x4 accg[4][2] = {};
    f32x4 accu[4][2] = {};

    for (int k0 = 0; k0 < HDIM; k0 += 64) {
#pragma unroll
        for (int i = 0; i < 4; ++i) {
            GLD16(aptr[i], (char*)As + (wid * 4 + i) * 1024);
            aptr[i] += 128;
        }
#pragma unroll
        for (int i = 0; i < 2; ++i) {
            GLD16(bgptr[i], (char*)Bg + (wid * 2 + i) * 1024);
            GLD16(buptr[i], (char*)Bu + (wid * 2 + i) * 1024);
            bgptr[i] += 128; buptr[i] += 128;
        }
        __syncthreads();
#pragma unroll
        for (int kk = 0; kk < 2; ++kk) {
            short8 af[4], bgf[2], buf_[2];
#pragma unroll
            for (int mf = 0; mf < 4; ++mf) {
                int row = m0 + mf * 16 + lr;
                int slot = (kk * 4 + lg) ^ (row & 7);
                af[mf] = *(const short8*)((const char*)As + row * 128 + slot * 16);
            }
#pragma unroll
            for (int nf = 0; nf < 2; ++nf) {
                int row = n0 + nf * 16 + lr;
                int slot = (kk * 4 + lg) ^ (row & 7);
                bgf[nf]  = *(const short8*)((const char*)Bg + row * 128 + slot * 16);
                buf_[nf] = *(const short8*)((const char*)Bu + row * 128 + slot * 16);
            }
#pragma unroll
            for (int mf = 0; mf < 4; ++mf)
#pragma unroll
                for (int nf = 0; nf < 2; ++nf) {
                    accg[mf][nf] = __builtin_amdgcn_mfma_f32_16x16x32_bf16(af[mf], bgf[nf],  accg[mf][nf], 0, 0, 0);
                    accu[mf][nf] = __builtin_amdgcn_mfma_f32_16x16x32_bf16(af[mf], buf_[nf], accu[mf][nf], 0, 0, 0);
                }
        }
        __syncthreads();
    }

    // epilogue: C/D layout col=lane&15, row=4*(lane>>4)+reg
#pragma unroll
    for (int mf = 0; mf < 4; ++mf) {
#pragma unroll
        for (int j = 0; j < 4; ++j) {
            int row = bm0 + m0 + mf * 16 + lg * 4 + j;
            if (row >= nrows) continue;
            int outrow = SH ? row : plist[row];
            u16* dst = hout + (size_t)outrow * IDIM + bn0 + n0 + lr;
#pragma unroll
            for (int nf = 0; nf < 2; ++nf) {
                float g = accg[mf][nf][j], u = accu[mf][nf][j];
                float sg = g / (1.f + __expf(-g));
                dst[nf * 16] = f2bf(sg * u);
            }
        }
    }
}

// ---------------- routed down: slot0 -> y0 (bf16), slot1 -> y1 (bf16); no atomics ----------------
__global__ __launch_bounds__(256)
void down_routed(const u16* __restrict__ Hp,      // [2T,I]
                 const u16* __restrict__ WdT,     // [E,H,I]
                 u16* __restrict__ y0,            // [T,H]
                 u16* __restrict__ y1,            // [T,H]
                 const float* __restrict__ wpair,
                 const int* __restrict__ counts,
                 const int* __restrict__ pair_id)
{
    const int e = blockIdx.z;
    const int nrows = counts[e];
    const int bm0 = blockIdx.y * 128;
    if (bm0 >= nrows) return;
    const int bn0 = blockIdx.x * 128;
    const u16* wdT = WdT + (size_t)e * HDIM * IDIM;
    const int* plist = pair_id + e * T_TOK;

    __shared__ __attribute__((aligned(16))) short As[128 * 64];  // 16 KB
    __shared__ __attribute__((aligned(16))) short Bs[128 * 64];  // 16 KB

    const int tid = threadIdx.x;
    const int lane = tid & 63;
    const int wid = tid >> 6;

    const char* aptr[4];
#pragma unroll
    for (int i = 0; i < 4; ++i) {
        int r = (wid * 4 + i) * 8 + (lane >> 3);
        int row = bm0 + r;
        int srow = (row < nrows) ? plist[row] : 0;
        int cslot = ((lane & 7) ^ (r & 7)) * 8;
        aptr[i] = (const char*)(Hp + (size_t)srow * IDIM + cslot);
    }
    const char* bptr[4];
#pragma unroll
    for (int i = 0; i < 4; ++i) {
        int r = (wid * 4 + i) * 8 + (lane >> 3);
        int cslot = ((lane & 7) ^ (r & 7)) * 8;
        bptr[i] = (const char*)(wdT + (size_t)(bn0 + r) * IDIM + cslot);
    }

    const int wm = wid >> 1, wn = wid & 1;
    const int m0 = wm * 64, n0 = wn * 64;
    const int lr = lane & 15, lg = lane >> 4;

    f32x4 acc[4][4] = {};

    for (int k0 = 0; k0 < IDIM; k0 += 64) {
#pragma unroll
        for (int i = 0; i < 4; ++i) {
            GLD16(aptr[i], (char*)As + (wid * 4 + i) * 1024);
            GLD16(bptr[i], (char*)Bs + (wid * 4 + i) * 1024);
            aptr[i] += 128; bptr[i] += 128;
        }
        __syncthreads();
#pragma unroll
        for (int kk = 0; kk < 2; ++kk) {
            short8 af[4], bf[4];
#pragma unroll
            for (int mf = 0; mf < 4; ++mf) {
                int row = m0 + mf * 16 + lr;
                int slot = (kk * 4 + lg) ^ (row & 7);
                af[mf] = *(const short8*)((const char*)As + row * 128 + slot * 16);
            }
#pragma unroll
            for (int nf = 0; nf < 4; ++nf) {
                int row = n0 + nf * 16 + lr;
                int slot = (kk * 4 + lg) ^ (row & 7);
                bf[nf] = *(const short8*)((const char*)Bs + row * 128 + slot * 16);
            }
#pragma unroll
            for (int mf = 0; mf < 4; ++mf)
#pragma unroll
                for (int nf = 0; nf < 4; ++nf)
                    acc[mf][nf] = __builtin_amdgcn_mfma_f32_16x16x32_bf16(af[mf], bf[nf], acc[mf][nf], 0, 0, 0);
        }
        __syncthreads();
    }

#pragma unroll
    for (int mf = 0; mf < 4; ++mf) {
#pragma unroll
        for (int j = 0; j < 4; ++j) {
            int row = bm0 + m0 + mf * 16 + lg * 4 + j;
            if (row >= nrows) continue;
            int p = plist[row];
            int t = p >> 1;
            float w = wpair[p];
            u16* dst = ((p & 1) ? y1 : y0) + (size_t)t * HDIM + bn0 + n0 + lr;
#pragma unroll
            for (int nf = 0; nf < 4; ++nf)
                dst[nf * 16] = f2bf(acc[mf][nf][j] * w);
        }
    }
}

// ---------------- shared down + combine: out = hs@swd + y0 + y1 (write-only out) ----------------
__global__ __launch_bounds__(256)
void down_shared_combine(const u16* __restrict__ Hs,   // [T,I]
                         const u16* __restrict__ swdT, // [H,I]
                         const u16* __restrict__ y0,   // [T,H]
                         const u16* __restrict__ y1,   // [T,H]
                         float* __restrict__ out)      // [T,H]
{
    const int bm0 = blockIdx.y * 128;
    const int bn0 = blockIdx.x * 128;

    __shared__ __attribute__((aligned(16))) short As[128 * 64];
    __shared__ __attribute__((aligned(16))) short Bs[128 * 64];

    const int tid = threadIdx.x;
    const int lane = tid & 63;
    const int wid = tid >> 6;

    const char* aptr[4];
#pragma unroll
    for (int i = 0; i < 4; ++i) {
        int r = (wid * 4 + i) * 8 + (lane >> 3);
        int cslot = ((lane & 7) ^ (r & 7)) * 8;
        aptr[i] = (const char*)(Hs + (size_t)(bm0 + r) * IDIM + cslot);
    }
    const char* bptr[4];
#pragma unroll
    for (int i = 0; i < 4; ++i) {
        int r = (wid * 4 + i) * 8 + (lane >> 3);
        int cslot = ((lane & 7) ^ (r & 7)) * 8;
        bptr[i] = (const char*)(swdT + (size_t)(bn0 + r) * IDIM + cslot);
    }

    const int wm = wid >> 1, wn = wid & 1;
    const int m0 = wm * 64, n0 = wn * 64;
    const int lr = lane & 15, lg = lane >> 4;

    f32x4 acc[4][4] = {};

    for (int k0 = 0; k0 < IDIM; k0 += 64) {
#pragma unroll
        for (int i = 0; i < 4; ++i) {
            GLD16(aptr[i], (char*)As + (wid * 4 + i) * 1024);
            GLD16(bptr[i], (char*)Bs + (wid * 4 + i) * 1024);
            aptr[i] += 128; bptr[i] += 128;
        }
        __syncthreads();
#pragma unroll
        for (int kk = 0; kk < 2; ++kk) {
            short8 af[4], bf[4];
#pragma unroll
            for (int mf = 0; mf < 4; ++mf) {
                int row = m0 + mf * 16 + lr;
                int slot = (kk * 4 + lg) ^ (row & 7);
                af[mf] = *(const short8*)((const char*)As + row * 128 + slot * 16);
            }
#pragma unroll
            for (int nf = 0; nf < 4; ++nf) {
                int row = n0 + nf * 16 + lr;
                int slot = (kk * 4 + lg) ^ (row & 7);
                bf[nf] = *(const short8*)((const char*)Bs + row * 128 + slot * 16);
            }
#pragma unroll
            for (int mf = 0; mf < 4; ++mf)
#pragma unroll
                for (int nf = 0; nf < 4; ++nf)
                    acc[mf][nf] = __builtin_amdgcn_mfma_f32_16x16x32_bf16(af[mf], bf[nf], acc[mf][nf], 0, 0, 0);
        }
        __syncthreads();
    }

#pragma unroll
    for (int mf = 0; mf < 4; ++mf) {
#pragma unroll
        for (int j = 0; j < 4; ++j) {
            int t = bm0 + m0 + mf * 16 + lg * 4 + j;
            float* dst = out + (size_t)t * HDIM + bn0 + n0 + lr;
            const u16* y0src = y0 + (size_t)t * HDIM + bn0 + n0 + lr;
            const u16* y1src = y1 + (size_t)t * HDIM + bn0 + n0 + lr;
#pragma unroll
            for (int nf = 0; nf < 4; ++nf)
                dst[nf * 16] = acc[mf][nf][j] + bf2f(y0src[nf * 16]) + bf2f(y1src[nf * 16]);
        }
    }
}

extern "C" void kernel_launch(void* const* d_in, const int* in_sizes, int n_in,
                              void* d_out, int out_size, void* d_ws, size_t ws_size,
                              hipStream_t stream) {
    const float* X    = (const float*)d_in[0];
    const float* Wr   = (const float*)d_in[1];
    const float* bias = (const float*)d_in[2];
    const float* wg   = (const float*)d_in[3];
    const float* wu   = (const float*)d_in[4];
    const float* wdn  = (const float*)d_in[5];
    const float* swg  = (const float*)d_in[6];
    const float* swu  = (const float*)d_in[7];
    const float* swd  = (const float*)d_in[8];
    float* out = (float*)d_out;
    (void)in_sizes; (void)n_in; (void)out_size; (void)ws_size;

    char* ws = (char*)d_ws;
    const size_t MB = 1048576;
    int*   counts   = (int*)ws;                          // 32 B
    float* wpair    = (float*)(ws + 4096);               // 64 KB
    int*   pair_id  = (int*)(ws + 4096 + 65536);         // 256 KB
    int*   topk_ids = (int*)(ws + 524288);               // 32 KB
    u16* Xb   = (u16*)(ws + 1 * MB);                     // 16 MB [T,H]; y1 aliases after gateup
    u16* wgT  = (u16*)(ws + 17 * MB);                    // 8 MB [E,I,H]; y0 aliases wgT+wuT after gateup
    u16* wuT  = (u16*)(ws + 25 * MB);                    // 8 MB
    u16* wdnT = (u16*)(ws + 33 * MB);                    // 8 MB [E,H,I]
    u16* swgT = (u16*)(ws + 41 * MB);                    // 1 MB [I,H]
    u16* swuT = (u16*)(ws + 42 * MB);                    // 1 MB
    u16* swdT = (u16*)(ws + 43 * MB);                    // 1 MB [H,I]
    u16* hs   = (u16*)(ws + 44 * MB);                    // 8 MB [T,I]
    u16* hp   = (u16*)(ws + 52 * MB);                    // 16 MB [2T,I]
    u16* y1   = Xb;                                      // Xb dead after gateup_all
    u16* y0   = wgT;                                     // wgT/wuT dead after gateup_all (16 MB span)

    // router (2048 blocks) + 27 weight transposes (3456 blocks) in one launch
    prologue<<<2048 + 27 * 128, 256, 0, stream>>>(
        X, Wr, bias, Xb, wpair, topk_ids,
        wg, wu, wdn, swg, swu, swd, wgT, wuT, wdnT, swgT, swuT, swdT);
    build_lists<<<NEXP, 256, 0, stream>>>(topk_ids, counts, pair_id);

    // col-block fastest (blockIdx.x) -> per-XCD weight-slice L2 reuse
    gateup_all<<<dim3(IDIM / 64, T_TOK / 128, NEXP + 1), 256, 0, stream>>>(
        Xb, wgT, wuT, swgT, swuT, hs, hp, counts, pair_id);

    down_routed<<<dim3(HDIM / 128, T_TOK / 128, NEXP), 256, 0, stream>>>(
        hp, wdnT, y0, y1, wpair, counts, pair_id);

    down_shared_combine<<<dim3(HDIM / 128, T_TOK / 128, 1), 256, 0, stream>>>(
        hs, swdT, y0, y1, out);
}

// Round 10
// 194.023 us; speedup vs baseline: 1.9651x; 1.0509x over previous
//
#include <hip/hip_runtime.h>
#include <math.h>
#include <stdint.h>

#define T_TOK 8192
#define HDIM 1024
#define IDIM 512
#define NEXP 8
#define NGRP 2
#define EPG 4

typedef unsigned short u16;
typedef __attribute__((ext_vector_type(8))) short short8;   // 8 bf16 in 4 VGPRs
typedef __attribute__((ext_vector_type(4))) float f32x4;

// async global->LDS, 16B per lane; LDS dest is wave-uniform base (HW adds lane*16)
#define GLD16(gp, lp) __builtin_amdgcn_global_load_lds(                        \
    (const __attribute__((address_space(1))) unsigned int*)(gp),               \
    (__attribute__((address_space(3))) unsigned int*)(lp), 16, 0, 0)

__device__ __forceinline__ u16 f2bf(float f) {  // RNE float->bf16
    unsigned int u = __float_as_uint(f);
    u += 0x7fffu + ((u >> 16) & 1u);
    return (u16)(u >> 16);
}
__device__ __forceinline__ float bf2f(u16 v) {
    return __uint_as_float(((unsigned int)v) << 16);
}

// ---------------- prologue: router (blocks 0..2047) + weight transposes (2048..5503) ----------------
__global__ __launch_bounds__(256)
void prologue(const float* __restrict__ X,
              const float* __restrict__ Wr, const float* __restrict__ bias,
              u16* __restrict__ Xb, float* __restrict__ wpair, int* __restrict__ topk_ids,
              const float* __restrict__ wg,  const float* __restrict__ wu,
              const float* __restrict__ wdn, const float* __restrict__ swg,
              const float* __restrict__ swu, const float* __restrict__ swd,
              u16* __restrict__ wgT, u16* __restrict__ wuT, u16* __restrict__ wdnT,
              u16* __restrict__ swgT, u16* __restrict__ swuT, u16* __restrict__ swdT)
{
    __shared__ float tile[64][65];
    const int bid = blockIdx.x;

    if (bid < 2048) {
        // ---- router: one wave per token; no atomics ----
        int wave = threadIdx.x >> 6;
        int lane = threadIdx.x & 63;
        int t = bid * 4 + wave;

        float acc[NEXP];
#pragma unroll
        for (int e = 0; e < NEXP; ++e) acc[e] = 0.f;

        const float4* X4 = (const float4*)(X + (size_t)t * HDIM);
#pragma unroll
        for (int jj = 0; jj < 4; ++jj) {
            float4 xv = X4[lane + jj * 64];
            ushort4 bv;
            bv.x = f2bf(xv.x); bv.y = f2bf(xv.y); bv.z = f2bf(xv.z); bv.w = f2bf(xv.w);
            *(ushort4*)(Xb + (size_t)t * HDIM + (size_t)(lane + jj * 64) * 4) = bv;
#pragma unroll
            for (int e = 0; e < NEXP; ++e) {
                const float4* W4 = (const float4*)(Wr + (size_t)e * HDIM);
                float4 wv = W4[lane + jj * 64];
                acc[e] += xv.x * wv.x + xv.y * wv.y + xv.z * wv.z + xv.w * wv.w;
            }
        }
#pragma unroll
        for (int e = 0; e < NEXP; ++e) {
#pragma unroll
            for (int off = 32; off >= 1; off >>= 1)
                acc[e] += __shfl_xor(acc[e], off, 64);
        }

        if (lane == 0) {
            float s[NEXP], b[NEXP];
#pragma unroll
            for (int e = 0; e < NEXP; ++e) {
                s[e] = 1.f / (1.f + expf(-acc[e]));
                b[e] = s[e] + bias[e];
            }
            float gs[NGRP];
#pragma unroll
            for (int g = 0; g < NGRP; ++g) {
                float m1 = -1e30f, m2 = -1e30f;
#pragma unroll
                for (int j = 0; j < EPG; ++j) {
                    float v = b[g * EPG + j];
                    if (v > m1) { m2 = m1; m1 = v; }
                    else if (v > m2) { m2 = v; }
                }
                gs[g] = m1 + m2;
            }
            int bg = (gs[1] > gs[0]) ? 1 : 0;
            float masked[NEXP];
#pragma unroll
            for (int e = 0; e < NEXP; ++e)
                masked[e] = ((e >> 2) == bg) ? b[e] : 0.0f;
            int i0 = 0; float v0 = masked[0];
#pragma unroll
            for (int e = 1; e < NEXP; ++e)
                if (masked[e] > v0) { v0 = masked[e]; i0 = e; }
            int i1 = -1; float v1 = -1e30f;
#pragma unroll
            for (int e = 0; e < NEXP; ++e) {
                if (e == i0) continue;
                if (masked[e] > v1) { v1 = masked[e]; i1 = e; }
            }
            float w0 = s[i0], w1 = s[i1];
            float inv = 1.f / (w0 + w1 + 1e-20f);
            w0 *= inv; w1 *= inv;
            wpair[t * 2 + 0] = w0;
            wpair[t * 2 + 1] = w1;
            topk_ids[t] = i0 | (i1 << 8);
        }
        return;
    }

    // ---- transpose + fp32->bf16 convert: 27 matrices x 128 blocks ----
    int tb = bid - 2048;
    int m = tb >> 7;        // matrix id 0..26
    int i = tb & 127;
    const float* src; u16* dst; int R, C;
    const size_t EW = (size_t)HDIM * IDIM;
    if (m < 8)       { src = wg  + (size_t)m * EW;        dst = wgT  + (size_t)m * EW;        R = HDIM; C = IDIM; }
    else if (m < 16) { src = wu  + (size_t)(m - 8) * EW;  dst = wuT  + (size_t)(m - 8) * EW;  R = HDIM; C = IDIM; }
    else if (m < 24) { src = wdn + (size_t)(m - 16) * EW; dst = wdnT + (size_t)(m - 16) * EW; R = IDIM; C = HDIM; }
    else if (m == 24){ src = swg; dst = swgT; R = HDIM; C = IDIM; }
    else if (m == 25){ src = swu; dst = swuT; R = HDIM; C = IDIM; }
    else             { src = swd; dst = swdT; R = IDIM; C = HDIM; }
    int r0, c0;
    if (R == HDIM) { r0 = (i & 15) * 64; c0 = (i >> 4) * 64; }   // 16 x 8 blocks
    else           { r0 = (i & 7) * 64;  c0 = (i >> 3) * 64; }   // 8 x 16 blocks

    int t = threadIdx.x;
    int row = t >> 2;
#pragma unroll
    for (int j = 0; j < 4; ++j) {
        int c = ((t & 3) + j * 4) * 4;
        *(float4*)&tile[row][c] = *(const float4*)(src + (size_t)(r0 + row) * C + c0 + c);
    }
    __syncthreads();
    int c = t >> 2;
    int rchunk = (t & 3) * 16;
    __attribute__((aligned(16))) u16 pack[16];
#pragma unroll
    for (int k = 0; k < 16; ++k)
        pack[k] = f2bf(tile[rchunk + k][c]);
    uint4* d4 = (uint4*)(dst + (size_t)(c0 + c) * R + r0 + rchunk);
    d4[0] = *(uint4*)&pack[0];
    d4[1] = *(uint4*)&pack[8];
}

// ---------------- build per-expert pair lists (deterministic compaction) ----------------
__global__ __launch_bounds__(256)
void build_lists(const int* __restrict__ topk_ids,
                 int* __restrict__ counts,
                 int* __restrict__ pair_id)
{
    const int e = blockIdx.x;
    const int tid = threadIdx.x;
    const int lane = tid & 63;
    const int wid = tid >> 6;
    __shared__ int wsum[4];
    __shared__ int rb;
    if (tid == 0) rb = 0;
    __syncthreads();

    int* dst = pair_id + e * T_TOK;
    for (int c0 = 0; c0 < T_TOK; c0 += 256) {
        int t = c0 + tid;
        int ids = topk_ids[t];
        bool m0 = (ids & 0xff) == e;
        bool m1 = ((ids >> 8) & 0xff) == e;
        unsigned long long b0 = __ballot(m0);
        unsigned long long b1 = __ballot(m1);
        int n0 = __popcll(b0);
        int n1 = __popcll(b1);
        if (lane == 0) wsum[wid] = n0 + n1;
        __syncthreads();
        int pre = 0, tot = 0;
#pragma unroll
        for (int w = 0; w < 4; ++w) {
            int v = wsum[w];
            if (w < wid) pre += v;
            tot += v;
        }
        int mybase = rb + pre;
        unsigned long long ltmask = (lane == 63) ? ~0ull >> 1 : ((1ull << lane) - 1);
        if (m0) dst[mybase + __popcll(b0 & ltmask)] = t * 2;
        if (m1) dst[mybase + n0 + __popcll(b1 & ltmask)] = t * 2 + 1;
        __syncthreads();
        if (tid == 0) rb += tot;
    }
    __syncthreads();
    if (tid == 0) counts[e] = rb;
}

// ---------------- merged gate/up MFMA GEMM + SiLU -> h (bf16) ----------------
// m97 structure (r6-proven), r9 grid (col-block fastest -> XCD weight locality).
// h for routed experts is written CONTIGUOUS per expert: row (ebase[e] + list_idx).
__global__ __launch_bounds__(256)
void gateup_all(const u16* __restrict__ Xb,
                const u16* __restrict__ WgT, const u16* __restrict__ WuT,     // [E,I,H]
                const u16* __restrict__ sWgT, const u16* __restrict__ sWuT,   // [I,H]
                u16* __restrict__ hs,   // [T,I]
                u16* __restrict__ hp,   // [2T,I] contiguous per expert
                const int* __restrict__ counts,
                const int* __restrict__ pair_id)
{
    const int z = blockIdx.z;
    const bool SH = (z == 0);
    const int e = z - 1;
    const int nrows = SH ? T_TOK : counts[e];
    const int bm0 = blockIdx.y * 128;
    if (bm0 >= nrows) return;
    const int bn0 = blockIdx.x * 64;
    const u16* wgT = SH ? sWgT : WgT + (size_t)e * HDIM * IDIM;
    const u16* wuT = SH ? sWuT : WuT + (size_t)e * HDIM * IDIM;
    const int* plist = SH ? nullptr : (pair_id + e * T_TOK);
    u16* hout = SH ? hs : hp;

    int ebase = 0;
    if (!SH) {
#pragma unroll
        for (int i = 0; i < NEXP; ++i) ebase += (i < e) ? counts[i] : 0;
    }

    __shared__ __attribute__((aligned(16))) short As[128 * 64];  // 16 KB
    __shared__ __attribute__((aligned(16))) short Bg[64 * 64];   // 8 KB
    __shared__ __attribute__((aligned(16))) short Bu[64 * 64];   // 8 KB

    const int tid = threadIdx.x;
    const int lane = tid & 63;
    const int wid = tid >> 6;

    const char* aptr[4];
#pragma unroll
    for (int i = 0; i < 4; ++i) {
        int r = (wid * 4 + i) * 8 + (lane >> 3);
        int row = bm0 + r;
        int srow;
        if (SH) srow = row;
        else    srow = (row < nrows) ? (plist[row] >> 1) : 0;
        int cslot = ((lane & 7) ^ (r & 7)) * 8;
        aptr[i] = (const char*)(Xb + (size_t)srow * HDIM + cslot);
    }
    const char* bgptr[2]; const char* buptr[2];
#pragma unroll
    for (int i = 0; i < 2; ++i) {
        int r = (wid * 2 + i) * 8 + (lane >> 3);
        int nn = bn0 + r;
        int cslot = ((lane & 7) ^ (r & 7)) * 8;
        bgptr[i] = (const char*)(wgT + (size_t)nn * HDIM + cslot);
        buptr[i] = (const char*)(wuT + (size_t)nn * HDIM + cslot);
    }

    const int wm = wid >> 1, wn = wid & 1;
    const int m0 = wm * 64, n0 = wn * 32;
    const int lr = lane & 15, lg = lane >> 4;

    f32x4 accg[4][2] = {};
    f32x4 accu[4][2] = {};

    for (int k0 = 0; k0 < HDIM; k0 += 64) {
#pragma unroll
        for (int i = 0; i < 4; ++i) {
            GLD16(aptr[i], (char*)As + (wid * 4 + i) * 1024);
            aptr[i] += 128;
        }
#pragma unroll
        for (int i = 0; i < 2; ++i) {
            GLD16(bgptr[i], (char*)Bg + (wid * 2 + i) * 1024);
            GLD16(buptr[i], (char*)Bu + (wid * 2 + i) * 1024);
            bgptr[i] += 128; buptr[i] += 128;
        }
        __syncthreads();
#pragma unroll
        for (int kk = 0; kk < 2; ++kk) {
            short8 af[4], bgf[2], buf_[2];
#pragma unroll
            for (int mf = 0; mf < 4; ++mf) {
                int row = m0 + mf * 16 + lr;
                int slot = (kk * 4 + lg) ^ (row & 7);
                af[mf] = *(const short8*)((const char*)As + row * 128 + slot * 16);
            }
#pragma unroll
            for (int nf = 0; nf < 2; ++nf) {
                int row = n0 + nf * 16 + lr;
                int slot = (kk * 4 + lg) ^ (row & 7);
                bgf[nf]  = *(const short8*)((const char*)Bg + row * 128 + slot * 16);
                buf_[nf] = *(const short8*)((const char*)Bu + row * 128 + slot * 16);
            }
#pragma unroll
            for (int mf = 0; mf < 4; ++mf)
#pragma unroll
                for (int nf = 0; nf < 2; ++nf) {
                    accg[mf][nf] = __builtin_amdgcn_mfma_f32_16x16x32_bf16(af[mf], bgf[nf],  accg[mf][nf], 0, 0, 0);
                    accu[mf][nf] = __builtin_amdgcn_mfma_f32_16x16x32_bf16(af[mf], buf_[nf], accu[mf][nf], 0, 0, 0);
                }
        }
        __syncthreads();
    }

    // epilogue: C/D layout col=lane&15, row=4*(lane>>4)+reg
#pragma unroll
    for (int mf = 0; mf < 4; ++mf) {
#pragma unroll
        for (int j = 0; j < 4; ++j) {
            int row = bm0 + m0 + mf * 16 + lg * 4 + j;
            if (row >= nrows) continue;
            int outrow = SH ? row : (ebase + row);   // contiguous per expert
            u16* dst = hout + (size_t)outrow * IDIM + bn0 + n0 + lr;
#pragma unroll
            for (int nf = 0; nf < 2; ++nf) {
                float g = accg[mf][nf][j], u = accu[mf][nf][j];
                float sg = g / (1.f + __expf(-g));
                dst[nf * 16] = f2bf(sg * u);
            }
        }
    }
}

// ---------------- routed down: contiguous A rows; slot0 -> y0, slot1 -> y1 (bf16) ----------------
__global__ __launch_bounds__(256)
void down_routed(const u16* __restrict__ Hp,      // [2T,I] contiguous per expert
                 const u16* __restrict__ WdT,     // [E,H,I]
                 u16* __restrict__ y0,            // [T,H]
                 u16* __restrict__ y1,            // [T,H]
                 const float* __restrict__ wpair,
                 const int* __restrict__ counts,
                 const int* __restrict__ pair_id)
{
    const int e = blockIdx.z;
    const int nrows = counts[e];
    const int bm0 = blockIdx.y * 128;
    if (bm0 >= nrows) return;
    const int bn0 = blockIdx.x * 128;
    const u16* wdT = WdT + (size_t)e * HDIM * IDIM;
    const int* plist = pair_id + e * T_TOK;

    int ebase = 0;
#pragma unroll
    for (int i = 0; i < NEXP; ++i) ebase += (i < e) ? counts[i] : 0;

    __shared__ __attribute__((aligned(16))) short As[128 * 64];  // 16 KB
    __shared__ __attribute__((aligned(16))) short Bs[128 * 64];  // 16 KB

    const int tid = threadIdx.x;
    const int lane = tid & 63;
    const int wid = tid >> 6;

    const char* aptr[4];
#pragma unroll
    for (int i = 0; i < 4; ++i) {
        int r = (wid * 4 + i) * 8 + (lane >> 3);
        int row = bm0 + r;
        int srow = ebase + ((row < nrows) ? row : 0);   // contiguous stream, no gather
        int cslot = ((lane & 7) ^ (r & 7)) * 8;
        aptr[i] = (const char*)(Hp + (size_t)srow * IDIM + cslot);
    }
    const char* bptr[4];
#pragma unroll
    for (int i = 0; i < 4; ++i) {
        int r = (wid * 4 + i) * 8 + (lane >> 3);
        int cslot = ((lane & 7) ^ (r & 7)) * 8;
        bptr[i] = (const char*)(wdT + (size_t)(bn0 + r) * IDIM + cslot);
    }

    const int wm = wid >> 1, wn = wid & 1;
    const int m0 = wm * 64, n0 = wn * 64;
    const int lr = lane & 15, lg = lane >> 4;

    f32x4 acc[4][4] = {};

    for (int k0 = 0; k0 < IDIM; k0 += 64) {
#pragma unroll
        for (int i = 0; i < 4; ++i) {
            GLD16(aptr[i], (char*)As + (wid * 4 + i) * 1024);
            GLD16(bptr[i], (char*)Bs + (wid * 4 + i) * 1024);
            aptr[i] += 128; bptr[i] += 128;
        }
        __syncthreads();
#pragma unroll
        for (int kk = 0; kk < 2; ++kk) {
            short8 af[4], bf[4];
#pragma unroll
            for (int mf = 0; mf < 4; ++mf) {
                int row = m0 + mf * 16 + lr;
                int slot = (kk * 4 + lg) ^ (row & 7);
                af[mf] = *(const short8*)((const char*)As + row * 128 + slot * 16);
            }
#pragma unroll
            for (int nf = 0; nf < 4; ++nf) {
                int row = n0 + nf * 16 + lr;
                int slot = (kk * 4 + lg) ^ (row & 7);
                bf[nf] = *(const short8*)((const char*)Bs + row * 128 + slot * 16);
            }
#pragma unroll
            for (int mf = 0; mf < 4; ++mf)
#pragma unroll
                for (int nf = 0; nf < 4; ++nf)
                    acc[mf][nf] = __builtin_amdgcn_mfma_f32_16x16x32_bf16(af[mf], bf[nf], acc[mf][nf], 0, 0, 0);
        }
        __syncthreads();
    }

#pragma unroll
    for (int mf = 0; mf < 4; ++mf) {
#pragma unroll
        for (int j = 0; j < 4; ++j) {
            int row = bm0 + m0 + mf * 16 + lg * 4 + j;
            if (row >= nrows) continue;
            int p = plist[row];
            int t = p >> 1;
            float w = wpair[p];
            u16* dst = ((p & 1) ? y1 : y0) + (size_t)t * HDIM + bn0 + n0 + lr;
#pragma unroll
            for (int nf = 0; nf < 4; ++nf)
                dst[nf * 16] = f2bf(acc[mf][nf][j] * w);
        }
    }
}

// ---------------- shared down + combine: out = hs@swd + y0 + y1 (write-only out) ----------------
__global__ __launch_bounds__(256)
void down_shared_combine(const u16* __restrict__ Hs,   // [T,I]
                         const u16* __restrict__ swdT, // [H,I]
                         const u16* __restrict__ y0,   // [T,H]
                         const u16* __restrict__ y1,   // [T,H]
                         float* __restrict__ out)      // [T,H]
{
    const int bm0 = blockIdx.y * 128;
    const int bn0 = blockIdx.x * 128;

    __shared__ __attribute__((aligned(16))) short As[128 * 64];
    __shared__ __attribute__((aligned(16))) short Bs[128 * 64];

    const int tid = threadIdx.x;
    const int lane = tid & 63;
    const int wid = tid >> 6;

    const char* aptr[4];
#pragma unroll
    for (int i = 0; i < 4; ++i) {
        int r = (wid * 4 + i) * 8 + (lane >> 3);
        int cslot = ((lane & 7) ^ (r & 7)) * 8;
        aptr[i] = (const char*)(Hs + (size_t)(bm0 + r) * IDIM + cslot);
    }
    const char* bptr[4];
#pragma unroll
    for (int i = 0; i < 4; ++i) {
        int r = (wid * 4 + i) * 8 + (lane >> 3);
        int cslot = ((lane & 7) ^ (r & 7)) * 8;
        bptr[i] = (const char*)(swdT + (size_t)(bn0 + r) * IDIM + cslot);
    }

    const int wm = wid >> 1, wn = wid & 1;
    const int m0 = wm * 64, n0 = wn * 64;
    const int lr = lane & 15, lg = lane >> 4;

    f32x4 acc[4][4] = {};

    for (int k0 = 0; k0 < IDIM; k0 += 64) {
#pragma unroll
        for (int i = 0; i < 4; ++i) {
            GLD16(aptr[i], (char*)As + (wid * 4 + i) * 1024);
            GLD16(bptr[i], (char*)Bs + (wid * 4 + i) * 1024);
            aptr[i] += 128; bptr[i] += 128;
        }
        __syncthreads();
#pragma unroll
        for (int kk = 0; kk < 2; ++kk) {
            short8 af[4], bf[4];
#pragma unroll
            for (int mf = 0; mf < 4; ++mf) {
                int row = m0 + mf * 16 + lr;
                int slot = (kk * 4 + lg) ^ (row & 7);
                af[mf] = *(const short8*)((const char*)As + row * 128 + slot * 16);
            }
#pragma unroll
            for (int nf = 0; nf < 4; ++nf) {
                int row = n0 + nf * 16 + lr;
                int slot = (kk * 4 + lg) ^ (row & 7);
                bf[nf] = *(const short8*)((const char*)Bs + row * 128 + slot * 16);
            }
#pragma unroll
            for (int mf = 0; mf < 4; ++mf)
#pragma unroll
                for (int nf = 0; nf < 4; ++nf)
                    acc[mf][nf] = __builtin_amdgcn_mfma_f32_16x16x32_bf16(af[mf], bf[nf], acc[mf][nf], 0, 0, 0);
        }
        __syncthreads();
    }

#pragma unroll
    for (int mf = 0; mf < 4; ++mf) {
#pragma unroll
        for (int j = 0; j < 4; ++j) {
            int t = bm0 + m0 + mf * 16 + lg * 4 + j;
            float* dst = out + (size_t)t * HDIM + bn0 + n0 + lr;
            const u16* y0src = y0 + (size_t)t * HDIM + bn0 + n0 + lr;
            const u16* y1src = y1 + (size_t)t * HDIM + bn0 + n0 + lr;
#pragma unroll
            for (int nf = 0; nf < 4; ++nf)
                dst[nf * 16] = acc[mf][nf][j] + bf2f(y0src[nf * 16]) + bf2f(y1src[nf * 16]);
        }
    }
}

extern "C" void kernel_launch(void* const* d_in, const int* in_sizes, int n_in,
                              void* d_out, int out_size, void* d_ws, size_t ws_size,
                              hipStream_t stream) {
    const float* X    = (const float*)d_in[0];
    const float* Wr   = (const float*)d_in[1];
    const float* bias = (const float*)d_in[2];
    const float* wg   = (const float*)d_in[3];
    const float* wu   = (const float*)d_in[4];
    const float* wdn  = (const float*)d_in[5];
    const float* swg  = (const float*)d_in[6];
    const float* swu  = (const float*)d_in[7];
    const float* swd  = (const float*)d_in[8];
    float* out = (float*)d_out;
    (void)in_sizes; (void)n_in; (void)out_size; (void)ws_size;

    char* ws = (char*)d_ws;
    const size_t MB = 1048576;
    int*   counts   = (int*)ws;                          // 32 B
    float* wpair    = (float*)(ws + 4096);               // 64 KB
    int*   pair_id  = (int*)(ws + 4096 + 65536);         // 256 KB
    int*   topk_ids = (int*)(ws + 524288);               // 32 KB
    u16* Xb   = (u16*)(ws + 1 * MB);                     // 16 MB [T,H]; y1 aliases after gateup
    u16* wgT  = (u16*)(ws + 17 * MB);                    // 8 MB [E,I,H]; y0 aliases wgT+wuT after gateup
    u16* wuT  = (u16*)(ws + 25 * MB);                    // 8 MB
    u16* wdnT = (u16*)(ws + 33 * MB);                    // 8 MB [E,H,I]
    u16* swgT = (u16*)(ws + 41 * MB);                    // 1 MB [I,H]
    u16* swuT = (u16*)(ws + 42 * MB);                    // 1 MB
    u16* swdT = (u16*)(ws + 43 * MB);                    // 1 MB [H,I]
    u16* hs   = (u16*)(ws + 44 * MB);                    // 8 MB [T,I]
    u16* hp   = (u16*)(ws + 52 * MB);                    // 16 MB [2T,I] contiguous per expert
    u16* y1   = Xb;                                      // Xb dead after gateup_all
    u16* y0   = wgT;                                     // wgT/wuT dead after gateup_all (16 MB span)

    // router (2048 blocks) + 27 weight transposes (3456 blocks) in one launch
    prologue<<<2048 + 27 * 128, 256, 0, stream>>>(
        X, Wr, bias, Xb, wpair, topk_ids,
        wg, wu, wdn, swg, swu, swd, wgT, wuT, wdnT, swgT, swuT, swdT);
    build_lists<<<NEXP, 256, 0, stream>>>(topk_ids, counts, pair_id);

    // col-block fastest (blockIdx.x) -> per-XCD weight-slice L2 reuse
    gateup_all<<<dim3(IDIM / 64, T_TOK / 128, NEXP + 1), 256, 0, stream>>>(
        Xb, wgT, wuT, swgT, swuT, hs, hp, counts, pair_id);

    down_routed<<<dim3(HDIM / 128, T_TOK / 128, NEXP), 256, 0, stream>>>(
        hp, wdnT, y0, y1, wpair, counts, pair_id);

    down_shared_combine<<<dim3(HDIM / 128, T_TOK / 128, 1), 256, 0, stream>>>(
        hs, swdT, y0, y1, out);
}

// Round 11
// 169.669 us; speedup vs baseline: 2.2472x; 1.1435x over previous
//
#include <hip/hip_runtime.h>
#include <math.h>
#include <stdint.h>

#define T_TOK 8192
#define HDIM 1024
#define IDIM 512
#define NEXP 8
#define NGRP 2
#define EPG 4

typedef unsigned short u16;
typedef __attribute__((ext_vector_type(8))) short short8;   // 8 bf16 in 4 VGPRs
typedef __attribute__((ext_vector_type(4))) float f32x4;

// async global->LDS, 16B per lane; LDS dest is wave-uniform base (HW adds lane*16)
#define GLD16(gp, lp) __builtin_amdgcn_global_load_lds(                        \
    (const __attribute__((address_space(1))) unsigned int*)(gp),               \
    (__attribute__((address_space(3))) unsigned int*)(lp), 16, 0, 0)

__device__ __forceinline__ u16 f2bf(float f) {  // RNE float->bf16
    unsigned int u = __float_as_uint(f);
    u += 0x7fffu + ((u >> 16) & 1u);
    return (u16)(u >> 16);
}
__device__ __forceinline__ float bf2f(u16 v) {
    return __uint_as_float(((unsigned int)v) << 16);
}

// ---------------- prologue: router (blocks 0..2047) + weight transposes (2048..5503) ----------------
__global__ __launch_bounds__(256)
void prologue(const float* __restrict__ X,
              const float* __restrict__ Wr, const float* __restrict__ bias,
              u16* __restrict__ Xb, float* __restrict__ wpair, int* __restrict__ topk_ids,
              const float* __restrict__ wg,  const float* __restrict__ wu,
              const float* __restrict__ wdn, const float* __restrict__ swg,
              const float* __restrict__ swu, const float* __restrict__ swd,
              u16* __restrict__ wgT, u16* __restrict__ wuT, u16* __restrict__ wdnT,
              u16* __restrict__ swgT, u16* __restrict__ swuT, u16* __restrict__ swdT)
{
    __shared__ float tile[64][65];
    const int bid = blockIdx.x;

    if (bid < 2048) {
        // ---- router: one wave per token; no atomics ----
        int wave = threadIdx.x >> 6;
        int lane = threadIdx.x & 63;
        int t = bid * 4 + wave;

        float acc[NEXP];
#pragma unroll
        for (int e = 0; e < NEXP; ++e) acc[e] = 0.f;

        const float4* X4 = (const float4*)(X + (size_t)t * HDIM);
#pragma unroll
        for (int jj = 0; jj < 4; ++jj) {
            float4 xv = X4[lane + jj * 64];
            ushort4 bv;
            bv.x = f2bf(xv.x); bv.y = f2bf(xv.y); bv.z = f2bf(xv.z); bv.w = f2bf(xv.w);
            *(ushort4*)(Xb + (size_t)t * HDIM + (size_t)(lane + jj * 64) * 4) = bv;
#pragma unroll
            for (int e = 0; e < NEXP; ++e) {
                const float4* W4 = (const float4*)(Wr + (size_t)e * HDIM);
                float4 wv = W4[lane + jj * 64];
                acc[e] += xv.x * wv.x + xv.y * wv.y + xv.z * wv.z + xv.w * wv.w;
            }
        }
#pragma unroll
        for (int e = 0; e < NEXP; ++e) {
#pragma unroll
            for (int off = 32; off >= 1; off >>= 1)
                acc[e] += __shfl_xor(acc[e], off, 64);
        }

        if (lane == 0) {
            float s[NEXP], b[NEXP];
#pragma unroll
            for (int e = 0; e < NEXP; ++e) {
                s[e] = 1.f / (1.f + expf(-acc[e]));
                b[e] = s[e] + bias[e];
            }
            float gs[NGRP];
#pragma unroll
            for (int g = 0; g < NGRP; ++g) {
                float m1 = -1e30f, m2 = -1e30f;
#pragma unroll
                for (int j = 0; j < EPG; ++j) {
                    float v = b[g * EPG + j];
                    if (v > m1) { m2 = m1; m1 = v; }
                    else if (v > m2) { m2 = v; }
                }
                gs[g] = m1 + m2;
            }
            int bg = (gs[1] > gs[0]) ? 1 : 0;
            float masked[NEXP];
#pragma unroll
            for (int e = 0; e < NEXP; ++e)
                masked[e] = ((e >> 2) == bg) ? b[e] : 0.0f;
            int i0 = 0; float v0 = masked[0];
#pragma unroll
            for (int e = 1; e < NEXP; ++e)
                if (masked[e] > v0) { v0 = masked[e]; i0 = e; }
            int i1 = -1; float v1 = -1e30f;
#pragma unroll
            for (int e = 0; e < NEXP; ++e) {
                if (e == i0) continue;
                if (masked[e] > v1) { v1 = masked[e]; i1 = e; }
            }
            float w0 = s[i0], w1 = s[i1];
            float inv = 1.f / (w0 + w1 + 1e-20f);
            w0 *= inv; w1 *= inv;
            wpair[t * 2 + 0] = w0;
            wpair[t * 2 + 1] = w1;
            topk_ids[t] = i0 | (i1 << 8);
        }
        return;
    }

    // ---- transpose + fp32->bf16 convert: 27 matrices x 128 blocks ----
    int tb = bid - 2048;
    int m = tb >> 7;        // matrix id 0..26
    int i = tb & 127;
    const float* src; u16* dst; int R, C;
    const size_t EW = (size_t)HDIM * IDIM;
    if (m < 8)       { src = wg  + (size_t)m * EW;        dst = wgT  + (size_t)m * EW;        R = HDIM; C = IDIM; }
    else if (m < 16) { src = wu  + (size_t)(m - 8) * EW;  dst = wuT  + (size_t)(m - 8) * EW;  R = HDIM; C = IDIM; }
    else if (m < 24) { src = wdn + (size_t)(m - 16) * EW; dst = wdnT + (size_t)(m - 16) * EW; R = IDIM; C = HDIM; }
    else if (m == 24){ src = swg; dst = swgT; R = HDIM; C = IDIM; }
    else if (m == 25){ src = swu; dst = swuT; R = HDIM; C = IDIM; }
    else             { src = swd; dst = swdT; R = IDIM; C = HDIM; }
    int r0, c0;
    if (R == HDIM) { r0 = (i & 15) * 64; c0 = (i >> 4) * 64; }   // 16 x 8 blocks
    else           { r0 = (i & 7) * 64;  c0 = (i >> 3) * 64; }   // 8 x 16 blocks

    int t = threadIdx.x;
    int row = t >> 2;
#pragma unroll
    for (int j = 0; j < 4; ++j) {
        int c = ((t & 3) + j * 4) * 4;
        *(float4*)&tile[row][c] = *(const float4*)(src + (size_t)(r0 + row) * C + c0 + c);
    }
    __syncthreads();
    int c = t >> 2;
    int rchunk = (t & 3) * 16;
    __attribute__((aligned(16))) u16 pack[16];
#pragma unroll
    for (int k = 0; k < 16; ++k)
        pack[k] = f2bf(tile[rchunk + k][c]);
    uint4* d4 = (uint4*)(dst + (size_t)(c0 + c) * R + r0 + rchunk);
    d4[0] = *(uint4*)&pack[0];
    d4[1] = *(uint4*)&pack[8];
}

// ---------------- build per-expert pair lists (deterministic compaction) ----------------
__global__ __launch_bounds__(256)
void build_lists(const int* __restrict__ topk_ids,
                 int* __restrict__ counts,
                 int* __restrict__ pair_id)
{
    const int e = blockIdx.x;
    const int tid = threadIdx.x;
    const int lane = tid & 63;
    const int wid = tid >> 6;
    __shared__ int wsum[4];
    __shared__ int rb;
    if (tid == 0) rb = 0;
    __syncthreads();

    int* dst = pair_id + e * T_TOK;
    for (int c0 = 0; c0 < T_TOK; c0 += 256) {
        int t = c0 + tid;
        int ids = topk_ids[t];
        bool m0 = (ids & 0xff) == e;
        bool m1 = ((ids >> 8) & 0xff) == e;
        unsigned long long b0 = __ballot(m0);
        unsigned long long b1 = __ballot(m1);
        int n0 = __popcll(b0);
        int n1 = __popcll(b1);
        if (lane == 0) wsum[wid] = n0 + n1;
        __syncthreads();
        int pre = 0, tot = 0;
#pragma unroll
        for (int w = 0; w < 4; ++w) {
            int v = wsum[w];
            if (w < wid) pre += v;
            tot += v;
        }
        int mybase = rb + pre;
        unsigned long long ltmask = (lane == 63) ? ~0ull >> 1 : ((1ull << lane) - 1);
        if (m0) dst[mybase + __popcll(b0 & ltmask)] = t * 2;
        if (m1) dst[mybase + n0 + __popcll(b1 & ltmask)] = t * 2 + 1;
        __syncthreads();
        if (tid == 0) rb += tot;
    }
    __syncthreads();
    if (tid == 0) counts[e] = rb;
}

// ---------------- merged gate/up MFMA GEMM + SiLU -> h (bf16) ----------------
// Block tile 128x64(x2), BK=64, 32KB LDS, m97 schedule — but 8 waves x (32x32) wave-tiles:
// halves acc VGPR/wave -> more resident waves/CU to hide the staging drain.
__global__ __launch_bounds__(512)
void gateup_all(const u16* __restrict__ Xb,
                const u16* __restrict__ WgT, const u16* __restrict__ WuT,     // [E,I,H]
                const u16* __restrict__ sWgT, const u16* __restrict__ sWuT,   // [I,H]
                u16* __restrict__ hs,   // [T,I]
                u16* __restrict__ hp,   // [2T,I] contiguous per expert
                const int* __restrict__ counts,
                const int* __restrict__ pair_id)
{
    const int z = blockIdx.z;
    const bool SH = (z == 0);
    const int e = z - 1;
    const int nrows = SH ? T_TOK : counts[e];
    const int bm0 = blockIdx.y * 128;
    if (bm0 >= nrows) return;
    const int bn0 = blockIdx.x * 64;
    const u16* wgT = SH ? sWgT : WgT + (size_t)e * HDIM * IDIM;
    const u16* wuT = SH ? sWuT : WuT + (size_t)e * HDIM * IDIM;
    const int* plist = SH ? nullptr : (pair_id + e * T_TOK);
    u16* hout = SH ? hs : hp;

    int ebase = 0;
    if (!SH) {
#pragma unroll
        for (int i = 0; i < NEXP; ++i) ebase += (i < e) ? counts[i] : 0;
    }

    __shared__ __attribute__((aligned(16))) short As[128 * 64];  // 16 KB
    __shared__ __attribute__((aligned(16))) short Bg[64 * 64];   // 8 KB
    __shared__ __attribute__((aligned(16))) short Bu[64 * 64];   // 8 KB

    const int tid = threadIdx.x;
    const int lane = tid & 63;
    const int wid = tid >> 6;           // 0..7

    // A staging: 16 insts of 1024B (8 rows each); wave does insts wid*2, wid*2+1
    const char* aptr[2];
#pragma unroll
    for (int i = 0; i < 2; ++i) {
        int g = wid * 2 + i;
        int r = g * 8 + (lane >> 3);
        int row = bm0 + r;
        int srow;
        if (SH) srow = row;
        else    srow = (row < nrows) ? (plist[row] >> 1) : 0;
        int cslot = ((lane & 7) ^ (r & 7)) * 8;
        aptr[i] = (const char*)(Xb + (size_t)srow * HDIM + cslot);
    }
    // B staging: 8 insts each; wave does inst wid
    const char* bgptr; const char* buptr;
    {
        int r = wid * 8 + (lane >> 3);
        int nn = bn0 + r;
        int cslot = ((lane & 7) ^ (r & 7)) * 8;
        bgptr = (const char*)(wgT + (size_t)nn * HDIM + cslot);
        buptr = (const char*)(wuT + (size_t)nn * HDIM + cslot);
    }

    const int wm = wid & 3, wn = wid >> 2;    // 4 M-tiles x 2 N-tiles
    const int m0 = wm * 32, n0 = wn * 32;
    const int lr = lane & 15, lg = lane >> 4;

    f32x4 accg[2][2] = {};
    f32x4 accu[2][2] = {};

    for (int k0 = 0; k0 < HDIM; k0 += 64) {
#pragma unroll
        for (int i = 0; i < 2; ++i) {
            GLD16(aptr[i], (char*)As + (wid * 2 + i) * 1024);
            aptr[i] += 128;
        }
        GLD16(bgptr, (char*)Bg + wid * 1024);
        GLD16(buptr, (char*)Bu + wid * 1024);
        bgptr += 128; buptr += 128;
        __syncthreads();
#pragma unroll
        for (int kk = 0; kk < 2; ++kk) {
            short8 af[2], bgf[2], buf_[2];
#pragma unroll
            for (int mf = 0; mf < 2; ++mf) {
                int row = m0 + mf * 16 + lr;
                int slot = (kk * 4 + lg) ^ (row & 7);
                af[mf] = *(const short8*)((const char*)As + row * 128 + slot * 16);
            }
#pragma unroll
            for (int nf = 0; nf < 2; ++nf) {
                int row = n0 + nf * 16 + lr;
                int slot = (kk * 4 + lg) ^ (row & 7);
                bgf[nf]  = *(const short8*)((const char*)Bg + row * 128 + slot * 16);
                buf_[nf] = *(const short8*)((const char*)Bu + row * 128 + slot * 16);
            }
#pragma unroll
            for (int mf = 0; mf < 2; ++mf)
#pragma unroll
                for (int nf = 0; nf < 2; ++nf) {
                    accg[mf][nf] = __builtin_amdgcn_mfma_f32_16x16x32_bf16(af[mf], bgf[nf],  accg[mf][nf], 0, 0, 0);
                    accu[mf][nf] = __builtin_amdgcn_mfma_f32_16x16x32_bf16(af[mf], buf_[nf], accu[mf][nf], 0, 0, 0);
                }
        }
        __syncthreads();
    }

    // epilogue: C/D layout col=lane&15, row=4*(lane>>4)+reg
#pragma unroll
    for (int mf = 0; mf < 2; ++mf) {
#pragma unroll
        for (int j = 0; j < 4; ++j) {
            int row = bm0 + m0 + mf * 16 + lg * 4 + j;
            if (row >= nrows) continue;
            int outrow = SH ? row : (ebase + row);   // contiguous per expert
            u16* dst = hout + (size_t)outrow * IDIM + bn0 + n0 + lr;
#pragma unroll
            for (int nf = 0; nf < 2; ++nf) {
                float g = accg[mf][nf][j], u = accu[mf][nf][j];
                float sg = g / (1.f + __expf(-g));
                dst[nf * 16] = f2bf(sg * u);
            }
        }
    }
}

// ---------------- routed down: contiguous A rows; slot0 -> y0, slot1 -> y1 (bf16) ----------------
// Block tile 128x128, 8 waves x (32x64) wave-tiles.
__global__ __launch_bounds__(512)
void down_routed(const u16* __restrict__ Hp,      // [2T,I] contiguous per expert
                 const u16* __restrict__ WdT,     // [E,H,I]
                 u16* __restrict__ y0,            // [T,H]
                 u16* __restrict__ y1,            // [T,H]
                 const float* __restrict__ wpair,
                 const int* __restrict__ counts,
                 const int* __restrict__ pair_id)
{
    const int e = blockIdx.z;
    const int nrows = counts[e];
    const int bm0 = blockIdx.y * 128;
    if (bm0 >= nrows) return;
    const int bn0 = blockIdx.x * 128;
    const u16* wdT = WdT + (size_t)e * HDIM * IDIM;
    const int* plist = pair_id + e * T_TOK;

    int ebase = 0;
#pragma unroll
    for (int i = 0; i < NEXP; ++i) ebase += (i < e) ? counts[i] : 0;

    __shared__ __attribute__((aligned(16))) short As[128 * 64];  // 16 KB
    __shared__ __attribute__((aligned(16))) short Bs[128 * 64];  // 16 KB

    const int tid = threadIdx.x;
    const int lane = tid & 63;
    const int wid = tid >> 6;

    const char* aptr[2]; const char* bptr[2];
#pragma unroll
    for (int i = 0; i < 2; ++i) {
        int g = wid * 2 + i;
        int r = g * 8 + (lane >> 3);
        int row = bm0 + r;
        int srow = ebase + ((row < nrows) ? row : 0);   // contiguous stream
        int cslot = ((lane & 7) ^ (r & 7)) * 8;
        aptr[i] = (const char*)(Hp + (size_t)srow * IDIM + cslot);
        bptr[i] = (const char*)(wdT + (size_t)(bn0 + r) * IDIM + cslot);
    }

    const int wm = wid & 3, wn = wid >> 2;    // 4 M-tiles x 2 N-tiles
    const int m0 = wm * 32, n0 = wn * 64;
    const int lr = lane & 15, lg = lane >> 4;

    f32x4 acc[2][4] = {};

    for (int k0 = 0; k0 < IDIM; k0 += 64) {
#pragma unroll
        for (int i = 0; i < 2; ++i) {
            GLD16(aptr[i], (char*)As + (wid * 2 + i) * 1024);
            GLD16(bptr[i], (char*)Bs + (wid * 2 + i) * 1024);
            aptr[i] += 128; bptr[i] += 128;
        }
        __syncthreads();
#pragma unroll
        for (int kk = 0; kk < 2; ++kk) {
            short8 af[2], bf[4];
#pragma unroll
            for (int mf = 0; mf < 2; ++mf) {
                int row = m0 + mf * 16 + lr;
                int slot = (kk * 4 + lg) ^ (row & 7);
                af[mf] = *(const short8*)((const char*)As + row * 128 + slot * 16);
            }
#pragma unroll
            for (int nf = 0; nf < 4; ++nf) {
                int row = n0 + nf * 16 + lr;
                int slot = (kk * 4 + lg) ^ (row & 7);
                bf[nf] = *(const short8*)((const char*)Bs + row * 128 + slot * 16);
            }
#pragma unroll
            for (int mf = 0; mf < 2; ++mf)
#pragma unroll
                for (int nf = 0; nf < 4; ++nf)
                    acc[mf][nf] = __builtin_amdgcn_mfma_f32_16x16x32_bf16(af[mf], bf[nf], acc[mf][nf], 0, 0, 0);
        }
        __syncthreads();
    }

#pragma unroll
    for (int mf = 0; mf < 2; ++mf) {
#pragma unroll
        for (int j = 0; j < 4; ++j) {
            int row = bm0 + m0 + mf * 16 + lg * 4 + j;
            if (row >= nrows) continue;
            int p = plist[row];
            int t = p >> 1;
            float w = wpair[p];
            u16* dst = ((p & 1) ? y1 : y0) + (size_t)t * HDIM + bn0 + n0 + lr;
#pragma unroll
            for (int nf = 0; nf < 4; ++nf)
                dst[nf * 16] = f2bf(acc[mf][nf][j] * w);
        }
    }
}

// ---------------- shared down + combine: out = hs@swd + y0 + y1 (write-only out) ----------------
__global__ __launch_bounds__(512)
void down_shared_combine(const u16* __restrict__ Hs,   // [T,I]
                         const u16* __restrict__ swdT, // [H,I]
                         const u16* __restrict__ y0,   // [T,H]
                         const u16* __restrict__ y1,   // [T,H]
                         float* __restrict__ out)      // [T,H]
{
    const int bm0 = blockIdx.y * 128;
    const int bn0 = blockIdx.x * 128;

    __shared__ __attribute__((aligned(16))) short As[128 * 64];
    __shared__ __attribute__((aligned(16))) short Bs[128 * 64];

    const int tid = threadIdx.x;
    const int lane = tid & 63;
    const int wid = tid >> 6;

    const char* aptr[2]; const char* bptr[2];
#pragma unroll
    for (int i = 0; i < 2; ++i) {
        int g = wid * 2 + i;
        int r = g * 8 + (lane >> 3);
        int cslot = ((lane & 7) ^ (r & 7)) * 8;
        aptr[i] = (const char*)(Hs + (size_t)(bm0 + r) * IDIM + cslot);
        bptr[i] = (const char*)(swdT + (size_t)(bn0 + r) * IDIM + cslot);
    }

    const int wm = wid & 3, wn = wid >> 2;
    const int m0 = wm * 32, n0 = wn * 64;
    const int lr = lane & 15, lg = lane >> 4;

    f32x4 acc[2][4] = {};

    for (int k0 = 0; k0 < IDIM; k0 += 64) {
#pragma unroll
        for (int i = 0; i < 2; ++i) {
            GLD16(aptr[i], (char*)As + (wid * 2 + i) * 1024);
            GLD16(bptr[i], (char*)Bs + (wid * 2 + i) * 1024);
            aptr[i] += 128; bptr[i] += 128;
        }
        __syncthreads();
#pragma unroll
        for (int kk = 0; kk < 2; ++kk) {
            short8 af[2], bf[4];
#pragma unroll
            for (int mf = 0; mf < 2; ++mf) {
                int row = m0 + mf * 16 + lr;
                int slot = (kk * 4 + lg) ^ (row & 7);
                af[mf] = *(const short8*)((const char*)As + row * 128 + slot * 16);
            }
#pragma unroll
            for (int nf = 0; nf < 4; ++nf) {
                int row = n0 + nf * 16 + lr;
                int slot = (kk * 4 + lg) ^ (row & 7);
                bf[nf] = *(const short8*)((const char*)Bs + row * 128 + slot * 16);
            }
#pragma unroll
            for (int mf = 0; mf < 2; ++mf)
#pragma unroll
                for (int nf = 0; nf < 4; ++nf)
                    acc[mf][nf] = __builtin_amdgcn_mfma_f32_16x16x32_bf16(af[mf], bf[nf], acc[mf][nf], 0, 0, 0);
        }
        __syncthreads();
    }

#pragma unroll
    for (int mf = 0; mf < 2; ++mf) {
#pragma unroll
        for (int j = 0; j < 4; ++j) {
            int t = bm0 + m0 + mf * 16 + lg * 4 + j;
            float* dst = out + (size_t)t * HDIM + bn0 + n0 + lr;
            const u16* y0src = y0 + (size_t)t * HDIM + bn0 + n0 + lr;
            const u16* y1src = y1 + (size_t)t * HDIM + bn0 + n0 + lr;
#pragma unroll
            for (int nf = 0; nf < 4; ++nf)
                dst[nf * 16] = acc[mf][nf][j] + bf2f(y0src[nf * 16]) + bf2f(y1src[nf * 16]);
        }
    }
}

extern "C" void kernel_launch(void* const* d_in, const int* in_sizes, int n_in,
                              void* d_out, int out_size, void* d_ws, size_t ws_size,
                              hipStream_t stream) {
    const float* X    = (const float*)d_in[0];
    const float* Wr   = (const float*)d_in[1];
    const float* bias = (const float*)d_in[2];
    const float* wg   = (const float*)d_in[3];
    const float* wu   = (const float*)d_in[4];
    const float* wdn  = (const float*)d_in[5];
    const float* swg  = (const float*)d_in[6];
    const float* swu  = (const float*)d_in[7];
    const float* swd  = (const float*)d_in[8];
    float* out = (float*)d_out;
    (void)in_sizes; (void)n_in; (void)out_size; (void)ws_size;

    char* ws = (char*)d_ws;
    const size_t MB = 1048576;
    int*   counts   = (int*)ws;                          // 32 B
    float* wpair    = (float*)(ws + 4096);               // 64 KB
    int*   pair_id  = (int*)(ws + 4096 + 65536);         // 256 KB
    int*   topk_ids = (int*)(ws + 524288);               // 32 KB
    u16* Xb   = (u16*)(ws + 1 * MB);                     // 16 MB [T,H]; y1 aliases after gateup
    u16* wgT  = (u16*)(ws + 17 * MB);                    // 8 MB [E,I,H]; y0 aliases wgT+wuT after gateup
    u16* wuT  = (u16*)(ws + 25 * MB);                    // 8 MB
    u16* wdnT = (u16*)(ws + 33 * MB);                    // 8 MB [E,H,I]
    u16* swgT = (u16*)(ws + 41 * MB);                    // 1 MB [I,H]
    u16* swuT = (u16*)(ws + 42 * MB);                    // 1 MB
    u16* swdT = (u16*)(ws + 43 * MB);                    // 1 MB [H,I]
    u16* hs   = (u16*)(ws + 44 * MB);                    // 8 MB [T,I]
    u16* hp   = (u16*)(ws + 52 * MB);                    // 16 MB [2T,I] contiguous per expert
    u16* y1   = Xb;                                      // Xb dead after gateup_all
    u16* y0   = wgT;                                     // wgT/wuT dead after gateup_all (16 MB span)

    // router (2048 blocks) + 27 weight transposes (3456 blocks) in one launch
    prologue<<<2048 + 27 * 128, 256, 0, stream>>>(
        X, Wr, bias, Xb, wpair, topk_ids,
        wg, wu, wdn, swg, swu, swd, wgT, wuT, wdnT, swgT, swuT, swdT);
    build_lists<<<NEXP, 256, 0, stream>>>(topk_ids, counts, pair_id);

    // col-block fastest (blockIdx.x) -> per-XCD weight-slice L2 reuse
    gateup_all<<<dim3(IDIM / 64, T_TOK / 128, NEXP + 1), 512, 0, stream>>>(
        Xb, wgT, wuT, swgT, swuT, hs, hp, counts, pair_id);

    down_routed<<<dim3(HDIM / 128, T_TOK / 128, NEXP), 512, 0, stream>>>(
        hp, wdnT, y0, y1, wpair, counts, pair_id);

    down_shared_combine<<<dim3(HDIM / 128, T_TOK / 128, 1), 512, 0, stream>>>(
        hs, swdT, y0, y1, out);
}